// Round 7
// baseline (520.560 us; speedup 1.0000x reference)
//
#include <hip/hip_runtime.h>
#include <math.h>

#define BATCH 128
#define NNODE 1024
#define EG 16384
#define F_IN 64
#define HID 128
#define C1 64
#define C2 32
#define NCLS 4
#define POWER_ITERS 50
#define BN (BATCH * NNODE)
#define RMAX 28
#define NORM_EVERY 5

typedef float f32x4 __attribute__((ext_vector_type(4)));
typedef __bf16 bf16x8 __attribute__((ext_vector_type(8)));
typedef unsigned short u16x4 __attribute__((ext_vector_type(4)));

__device__ inline unsigned short f2bf(float f) {   // round-to-nearest-even
    unsigned int u = __float_as_uint(f);
    u += 0x7fffu + ((u >> 16) & 1u);
    return (unsigned short)(u >> 16);
}
__device__ inline float bf2f(unsigned short h) {
    return __uint_as_float((unsigned int)h << 16);
}

// ---------------------------------------------------------------------------
// CSR build (by dst), single block. Emits:
//   pk  {raw_w, src}    + ptr  (true)    -> lmax
//   pk2 {relu_w, src*64} + ptr2 (padded to x4 with zero-weight edges) -> prop
// ---------------------------------------------------------------------------
__global__ __launch_bounds__(1024) void k_csr(
    const int* __restrict__ ei, const float* __restrict__ ew,
    int* __restrict__ ptr_g, int* __restrict__ ptr2_g,
    float* __restrict__ dgr_g, float* __restrict__ dgl_g,
    int2* __restrict__ packed, int2* __restrict__ packed2)
{
    __shared__ int   cnt[NNODE];
    __shared__ float dgr[NNODE];
    __shared__ float dgl[NNODE];
    __shared__ int   s[NNODE];
    __shared__ int   s2[NNODE];
    __shared__ int   base[NNODE];
    __shared__ int   base2[NNODE];
    const int t = threadIdx.x;

    cnt[t] = 0; dgr[t] = 0.f; dgl[t] = 0.f;

    int es[16], ed[16];
    float w[16];
#pragma unroll
    for (int i = 0; i < 16; ++i) {
        const int e = i * 1024 + t;
        es[i] = ei[e];
        ed[i] = ei[EG + e];
        w[i]  = ew[e];
    }
    __syncthreads();
#pragma unroll
    for (int i = 0; i < 16; ++i) {
        atomicAdd(&cnt[ed[i]], 1);
        atomicAdd(&dgr[es[i]], w[i]);
        atomicAdd(&dgl[es[i]], fmaxf(w[i], 0.f));
    }
    __syncthreads();
    dgr_g[t] = dgr[t];
    dgl_g[t] = dgl[t];

    const int v  = cnt[t];
    const int v4 = (v + 3) & ~3;
    s[t] = v; s2[t] = v4;
    __syncthreads();
    for (int o = 1; o < 1024; o <<= 1) {
        const int a  = (t >= o) ? s[t - o]  : 0;
        const int a2 = (t >= o) ? s2[t - o] : 0;
        __syncthreads();
        s[t] += a; s2[t] += a2;
        __syncthreads();
    }
    const int excl  = s[t]  - v;
    const int excl2 = s2[t] - v4;
    ptr_g[t]  = excl;  base[t]  = excl;
    ptr2_g[t] = excl2; base2[t] = excl2;
    if (t == 1023) { ptr_g[1024] = s[1023]; ptr2_g[1024] = s2[1023]; }
    __syncthreads();

#pragma unroll
    for (int i = 0; i < 16; ++i) {
        const int p  = atomicAdd(&base[ed[i]],  1);
        const int p2 = atomicAdd(&base2[ed[i]], 1);
        packed[p]   = make_int2(__float_as_int(w[i]), es[i]);
        packed2[p2] = make_int2(__float_as_int(fmaxf(w[i], 0.f)), es[i] << 6);
    }
    // zero-weight padding (disjoint slots; gathers hit row 0 with w=0)
    for (int j = excl2 + v; j < excl2 + v4; ++j)
        packed2[j] = make_int2(0, 0);
}

// ---------------------------------------------------------------------------
// Weight conversion WITH lambda-scale folding (runs after lmax finishes):
//   h = x(W0-W1+W2) + y1*s(W1-4W2) + y2*2s^2*W2,  y1=Lx, y2=L^2 x, s=2/lmax.
// ---------------------------------------------------------------------------
__global__ __launch_bounds__(256) void k_cvtw(
    const float* __restrict__ chebW, const float* __restrict__ convW,
    const float* __restrict__ scal,
    unsigned short* __restrict__ wcatT, unsigned short* __restrict__ cvw)
{
    const int i = blockIdx.x * 256 + threadIdx.x;
    const float s = scal[1];
    if (i < 24576) {
        const int n = i / 192, kk = i % 192;
        const int k = kk & 63;
        const float w0 = chebW[k * 128 + n];
        const float w1 = chebW[8192 + k * 128 + n];
        const float w2 = chebW[16384 + k * 128 + n];
        float val;
        if (kk < 64)       val = w0 - w1 + w2;
        else if (kk < 128) val = s * (w1 - 4.f * w2);
        else               val = 2.f * s * s * w2;
        wcatT[i] = f2bf(val);
    }
    const int j = i - 24576;
    if (j >= 0 && j < 8192) cvw[j] = f2bf(convW[j]);
}

// ---------------------------------------------------------------------------
// Fused kernel: block 0 = full 50-iter lmax power iteration (+Rayleigh);
// blocks 1..512 = (graph, 16-feat chunk): stage x fp32 in LDS, pass1 y1=Lx
// into LDS, pass2 y2=L y1 -- all gathers from LDS. Writes tcat bf16 slices
// 0,1,2 directly; NO fp32 y1 global round-trip. Numerics == previous round.
// ---------------------------------------------------------------------------
__global__ __launch_bounds__(1024) void k_prop2(
    const float* __restrict__ x,
    const int2* __restrict__ pk_raw, const int2* __restrict__ pk2,
    const int* __restrict__ ptrg, const int* __restrict__ ptr2g,
    const float* __restrict__ dgr, const float* __restrict__ dgl,
    float* __restrict__ scal, unsigned short* __restrict__ tcat)
{
    __shared__ float smem[32768];   // 128KB: xs[16K] | ys[16K]; block0: vA/vB/red
    const int t = threadIdx.x;

    if (blockIdx.x == 0) {
        // ---------------- lambda_max: 50 power iterations ----------------
        float* vA  = smem;
        float* vB  = smem + 1024;
        float* red = smem + 2048;
        const int p0 = ptrg[t], p1 = ptrg[t + 1];
        float w[RMAX];
        int src[RMAX];
#pragma unroll
        for (int i = 0; i < RMAX; ++i) {
            if (p0 + i < p1) {
                const int2 e = pk_raw[p0 + i];
                w[i] = __int_as_float(e.x);
                src[i] = e.y;
            } else {
                w[i] = 0.f;
                src[i] = 0;
            }
        }
        const int tp0 = p0 + RMAX;
        const float dgv = dgr[t];

        vA[t] = 0.03125f;   // 1/sqrt(1024)
        __syncthreads();

        float* cur = vA;
        float* nxt = vB;

        for (int it = 0; it < POWER_ITERS; ++it) {
            float u = dgv * cur[t];
#pragma unroll
            for (int i = 0; i < RMAX; ++i) u -= w[i] * cur[src[i]];
            for (int p = tp0; p < p1; ++p) {
                const int2 e = pk_raw[p];
                u -= __int_as_float(e.x) * cur[e.y];
            }
            if ((it % NORM_EVERY) == NORM_EVERY - 1) {
                float sr = u * u;
#pragma unroll
                for (int o = 32; o > 0; o >>= 1) sr += __shfl_down(sr, o, 64);
                if ((t & 63) == 0) red[t >> 6] = sr;
                __syncthreads();
                if (t < 64) {
                    float xs2 = (t < 16) ? red[t] : 0.f;
#pragma unroll
                    for (int o = 8; o > 0; o >>= 1) xs2 += __shfl_down(xs2, o, 64);
                    if (t == 0) red[16] = 1.0f / (sqrtf(xs2) + 1e-12f);
                }
                __syncthreads();
                nxt[t] = u * red[16];
            } else {
                nxt[t] = u;
            }
            __syncthreads();
            float* tmp = cur; cur = nxt; nxt = tmp;
        }

        float u = dgv * cur[t];
#pragma unroll
        for (int i = 0; i < RMAX; ++i) u -= w[i] * cur[src[i]];
        for (int p = tp0; p < p1; ++p) {
            const int2 e = pk_raw[p];
            u -= __int_as_float(e.x) * cur[e.y];
        }
        float sr = cur[t] * u;
#pragma unroll
        for (int o = 32; o > 0; o >>= 1) sr += __shfl_down(sr, o, 64);
        if ((t & 63) == 0) red[t >> 6] = sr;
        __syncthreads();
        if (t == 0) {
            float lm = 0.f;
            for (int i = 0; i < 16; ++i) lm += red[i];
            scal[0] = lm;
            scal[1] = 2.0f / lm;
        }
        return;
    }

    // ---------------- prop path: LDS-resident double Laplacian ----------------
    const int bb = blockIdx.x - 1;
    const int g  = bb >> 2;       // graph
    const int c  = bb & 3;        // 16-feature chunk
    float* xs = smem;             // [1024][16] fp32
    float* ys = smem + 16384;     // [1024][16] fp32

    const float* xg = x + (size_t)g * (NNODE * F_IN) + c * 16;
    unsigned short* tg = tcat + (size_t)g * NNODE * 192 + c * 16;

    // stage x chunk (aligned 64B lines) + emit tcat slice 0
    for (int i = t; i < 16384; i += 1024) {
        const int n = i >> 4, f = i & 15;
        const float xv = xg[n * 64 + f];
        xs[i] = xv;
        tg[n * 192 + f] = f2bf(xv);
    }
    __syncthreads();

    const int wv   = t >> 6;      // wave 0..15
    const int lane = t & 63;
    const int slot = lane >> 4;   // 4 edge slots
    const int f    = lane & 15;   // feature lane

    for (int pass = 0; pass < 2; ++pass) {
        const float* srcv = pass ? ys : xs;
        for (int d = wv; d < NNODE; d += 16) {
            const int q0 = __builtin_amdgcn_readfirstlane(ptr2g[d]);
            const int q1 = __builtin_amdgcn_readfirstlane(ptr2g[d + 1]);
            float acc = 0.f;
            for (int p = q0; p < q1; p += 4) {
                const int2 e = pk2[p + slot];
                const float vv =
                    *(const float*)((const char*)srcv + e.y + (f << 2));
                acc += __int_as_float(e.x) * vv;
            }
            acc += __shfl_xor(acc, 16, 64);
            acc += __shfl_xor(acc, 32, 64);
            const float xv = srcv[d * 16 + f];
            const float y = dgl[d] * xv - acc;
            if (lane < 16) {
                if (pass == 0) ys[d * 16 + f] = y;
                tg[d * 192 + (pass + 1) * 64 + f] = f2bf(y);
            }
        }
        __syncthreads();
    }
}

// ---------------------------------------------------------------------------
// Kernel 3: bf16 MFMA fused cheb-GEMM + conv1d. Output bf16.
// ---------------------------------------------------------------------------
__global__ __launch_bounds__(256) void k_cheb_mfma(
    const unsigned short* __restrict__ tcat,
    const unsigned short* __restrict__ wcatT,
    const unsigned short* __restrict__ cvw,
    const float* __restrict__ chebB, const float* __restrict__ convB,
    unsigned short* __restrict__ cout)
{
    __shared__ __align__(16) char smem[49152];   // Bs (48K) / hS(32K)+cwS(16K)
    __shared__ float cb_s[HID];
    __shared__ float cvb_s[C1];

    const int t    = threadIdx.x;
    const int lane = t & 63;
    const int wid  = t >> 6;
    const int l15  = lane & 15;
    const int l4   = lane >> 4;
    const int rbase = blockIdx.x * 128;
    const int bb = rbase >> 10;
    const int n0 = rbase & 1023;

    if (t < HID) cb_s[t] = chebB[t];
    if (t < C1)  cvb_s[t] = convB[t];

    // stage W^T [n=128][k-slot 0..23] with slot XOR (n&7) swizzle
    for (int it = 0; it < 12; ++it) {
        const int gslot = it * 256 + t;          // 0..3071
        const int n = gslot / 24, q = gslot % 24;
        const bf16x8 v = *(const bf16x8*)(wcatT + n * 192 + q * 8);
        *(bf16x8*)(smem + n * 384 + ((q ^ (n & 7)) << 4)) = v;
    }
    __syncthreads();

    // ---- Phase A: 16x16x32 MFMA, A-frags straight from global ----
    const int rw = rbase + wid * 32;
    f32x4 acc[2][8];
#pragma unroll
    for (int m = 0; m < 2; ++m)
#pragma unroll
        for (int n = 0; n < 8; ++n) acc[m][n] = (f32x4)(0.f);

    const unsigned short* ta = tcat + (size_t)(rw + l15) * 192 + l4 * 8;
    bf16x8 a0 = *(const bf16x8*)(ta);
    bf16x8 a1 = *(const bf16x8*)(ta + 16 * 192);

#pragma unroll
    for (int ks = 0; ks < 6; ++ks) {
        bf16x8 na0, na1;
        if (ks < 5) {
            na0 = *(const bf16x8*)(ta + (ks + 1) * 32);
            na1 = *(const bf16x8*)(ta + 16 * 192 + (ks + 1) * 32);
        }
        const int kb = ks * 4 + l4;
#pragma unroll
        for (int nb = 0; nb < 8; ++nb) {
            const int n = nb * 16 + l15;
            const bf16x8 bv =
                *(const bf16x8*)(smem + n * 384 + ((kb ^ (n & 7)) << 4));
            acc[0][nb] = __builtin_amdgcn_mfma_f32_16x16x32_bf16(
                a0, bv, acc[0][nb], 0, 0, 0);
            acc[1][nb] = __builtin_amdgcn_mfma_f32_16x16x32_bf16(
                a1, bv, acc[1][nb], 0, 0, 0);
        }
        a0 = na0; a1 = na1;
    }
    __syncthreads();   // Bs dead

    // write h (+cheb bias) as bf16 into hS[node][c] (swizzled), smem+0..32K
#pragma unroll
    for (int mf = 0; mf < 2; ++mf)
#pragma unroll
        for (int nb = 0; nb < 8; ++nb) {
            const int c = nb * 16 + l15;
            const int slot = c >> 3;
            const float cb = cb_s[c];
#pragma unroll
            for (int reg = 0; reg < 4; ++reg) {
                const int node = wid * 32 + mf * 16 + l4 * 4 + reg;
                *(unsigned short*)(smem + node * 256 +
                                   ((slot ^ (node & 7)) << 4) + (c & 7) * 2) =
                    f2bf(acc[mf][nb][reg] + cb);
            }
        }
    // stage convW [c1][128] bf16 swizzled at smem+32768
    for (int it = 0; it < 4; ++it) {
        const int gslot = it * 256 + t;          // 0..1023
        const int c1i = gslot >> 4, q = gslot & 15;
        const bf16x8 v = *(const bf16x8*)(cvw + c1i * 128 + q * 8);
        *(bf16x8*)(smem + 32768 + c1i * 256 + ((q ^ (c1i & 7)) << 4)) = v;
    }
    __syncthreads();

    // ---- Phase B: c1 x node = convW @ h^T ----
    f32x4 acc2[8];
#pragma unroll
    for (int n = 0; n < 8; ++n) acc2[n] = (f32x4)(0.f);

#pragma unroll
    for (int ks = 0; ks < 4; ++ks) {
        const int kb = ks * 4 + l4;
        const int c1a = wid * 16 + l15;
        const bf16x8 av = *(const bf16x8*)(smem + 32768 + c1a * 256 +
                                           ((kb ^ (c1a & 7)) << 4));
#pragma unroll
        for (int nb = 0; nb < 8; ++nb) {
            const int node = nb * 16 + l15;
            const bf16x8 bv =
                *(const bf16x8*)(smem + node * 256 + ((kb ^ (node & 7)) << 4));
            acc2[nb] = __builtin_amdgcn_mfma_f32_16x16x32_bf16(
                av, bv, acc2[nb], 0, 0, 0);
        }
    }

#pragma unroll
    for (int nb = 0; nb < 8; ++nb) {
        const int ng = n0 + nb * 16 + l15;
#pragma unroll
        for (int reg = 0; reg < 4; ++reg) {
            const int c1i = wid * 16 + l4 * 4 + reg;
            cout[(size_t)bb * (C1 * NNODE) + (size_t)c1i * NNODE + ng] =
                f2bf(fmaxf(acc2[nb][reg] + cvb_s[c1i], 0.f));
        }
    }
}

// ---------------------------------------------------------------------------
// Kernel 4: fc1 partials (K-split over 256-col chunks), bf16 input.
// ---------------------------------------------------------------------------
__global__ __launch_bounds__(256) void k_fc1(
    const unsigned short* __restrict__ cf, const float* __restrict__ W,
    float* __restrict__ part)
{
    __shared__ float Wt[256 * 33];
    const int t = threadIdx.x;
    const int g = blockIdx.x;
    const int k0 = g * 256;

    for (int i = t; i < 8192; i += 256) {
        const int j = i >> 8, k = i & 255;
        Wt[k * 33 + j] = W[(size_t)j * (C1 * NNODE) + k0 + k];
    }
    __syncthreads();

    const int j = t & 31, bg = t >> 5;
    float acc[16];
#pragma unroll
    for (int i = 0; i < 16; ++i) acc[i] = 0.f;

    const unsigned short* cb = cf + (size_t)(bg * 16) * (C1 * NNODE) + k0;
    for (int k4 = 0; k4 < 64; ++k4) {
        const int kb = k4 * 4;
        const float w0 = Wt[(kb + 0) * 33 + j];
        const float w1 = Wt[(kb + 1) * 33 + j];
        const float w2 = Wt[(kb + 2) * 33 + j];
        const float w3 = Wt[(kb + 3) * 33 + j];
#pragma unroll
        for (int i = 0; i < 16; ++i) {
            const u16x4 cv = *(const u16x4*)&cb[(size_t)i * (C1 * NNODE) + kb];
            acc[i] += bf2f(cv[0]) * w0 + bf2f(cv[1]) * w1 +
                      bf2f(cv[2]) * w2 + bf2f(cv[3]) * w3;
        }
    }
#pragma unroll
    for (int i = 0; i < 16; ++i)
        part[(size_t)g * 4096 + (size_t)(bg * 16 + i) * 32 + j] = acc[i];
}

__global__ __launch_bounds__(256) void k_red(
    const float* __restrict__ part, float* __restrict__ z)
{
    const int o = blockIdx.x * 256 + threadIdx.x;
    float s = 0.f;
    for (int g = 0; g < 256; ++g) s += part[(size_t)g * 4096 + o];
    z[o] = s;
}

__global__ __launch_bounds__(128) void k_head(
    const float* __restrict__ z, const float* __restrict__ b1,
    const float* __restrict__ W2, const float* __restrict__ b2,
    float* __restrict__ outp)
{
    const int b = threadIdx.x;
    float a[32];
#pragma unroll
    for (int j = 0; j < 32; ++j) a[j] = z[b * 32 + j] + b1[j];
    float l[4];
#pragma unroll
    for (int c = 0; c < 4; ++c) {
        float s = b2[c];
#pragma unroll
        for (int j = 0; j < 32; ++j) s += W2[c * 32 + j] * a[j];
        l[c] = s;
    }
    const float m = fmaxf(fmaxf(l[0], l[1]), fmaxf(l[2], l[3]));
    const float e0 = expf(l[0] - m), e1 = expf(l[1] - m);
    const float e2 = expf(l[2] - m), e3 = expf(l[3] - m);
    const float inv = 1.f / (e0 + e1 + e2 + e3);
    outp[b * 4 + 0] = e0 * inv;
    outp[b * 4 + 1] = e1 * inv;
    outp[b * 4 + 2] = e2 * inv;
    outp[b * 4 + 3] = e3 * inv;
}

// ---------------------------------------------------------------------------
extern "C" void kernel_launch(void* const* d_in, const int* in_sizes, int n_in,
                              void* d_out, int out_size, void* d_ws, size_t ws_size,
                              hipStream_t stream)
{
    const float* x     = (const float*)d_in[0];
    const int*   ei    = (const int*)d_in[1];
    const float* ew    = (const float*)d_in[2];
    const float* chebW = (const float*)d_in[3];
    const float* chebB = (const float*)d_in[4];
    const float* convW = (const float*)d_in[5];
    const float* convB = (const float*)d_in[6];
    const float* fc1W  = (const float*)d_in[7];
    const float* fc1B  = (const float*)d_in[8];
    const float* fc2W  = (const float*)d_in[9];
    const float* fc2B  = (const float*)d_in[10];
    float* out = (float*)d_out;

    char* ws = (char*)d_ws;
    float* scal = (float*)(ws + 0);
    char*  partb = ws + 8192;                      // 4MB multi-use region
    int*   ptr   = (int*)(partb + 8192);           // 1025 ints
    int*   ptr2  = (int*)(partb + 16384);          // 1025 ints
    float* dgr   = (float*)(partb + 24576);
    float* dgl   = (float*)(partb + 28672);
    int2*  pk    = (int2*)(partb + 32768);         // 128KB (raw w, src)
    int2*  pk2   = (int2*)(partb + 163840);        // 160KB (relu w, src*64, padded)
    unsigned short* wcatT = (unsigned short*)(partb + 327680);  // 48KB
    unsigned short* cvwB  = (unsigned short*)(partb + 393216);  // 16KB
    float* part = (float*)partb;                   // fc1 partials (after cheb)
    float* z    = (float*)(ws + 8192 + 4194304);
    unsigned short* tcat = (unsigned short*)(ws + 8192 + 4194304 + 65536); // 50.3MB
    unsigned short* cbuf = (unsigned short*)((char*)tcat + 50331648);      // 16MB

    k_csr<<<dim3(1), dim3(1024), 0, stream>>>(ei, ew, ptr, ptr2, dgr, dgl,
                                              pk, pk2);

    k_prop2<<<dim3(513), dim3(1024), 0, stream>>>(
        x, pk, pk2, ptr, ptr2, dgr, dgl, scal, tcat);

    k_cvtw<<<dim3(128), dim3(256), 0, stream>>>(chebW, convW, scal, wcatT, cvwB);

    k_cheb_mfma<<<dim3(BN / 128), dim3(256), 0, stream>>>(
        tcat, wcatT, cvwB, chebB, convB, cbuf);

    k_fc1<<<dim3(256), dim3(256), 0, stream>>>(cbuf, fc1W, part);
    k_red<<<dim3(16), dim3(256), 0, stream>>>(part, z);
    k_head<<<dim3(1), dim3(128), 0, stream>>>(z, fc1B, fc2W, fc2B, out);
}

// Round 10
// 319.057 us; speedup vs baseline: 1.6316x; 1.6316x over previous
//
#include <hip/hip_runtime.h>
#include <math.h>

#define BATCH 128
#define NNODE 1024
#define EG 16384
#define F_IN 64
#define HID 128
#define C1 64
#define C2 32
#define NCLS 4
#define POWER_ITERS 50
#define BN (BATCH * NNODE)
#define RMAX 28
#define NORM_EVERY 5

typedef float f32x4 __attribute__((ext_vector_type(4)));
typedef __bf16 bf16x8 __attribute__((ext_vector_type(8)));
typedef unsigned short u16x4 __attribute__((ext_vector_type(4)));
typedef unsigned short u16x8 __attribute__((ext_vector_type(8)));

__device__ inline unsigned short f2bf(float f) {   // round-to-nearest-even
    unsigned int u = __float_as_uint(f);
    u += 0x7fffu + ((u >> 16) & 1u);
    return (unsigned short)(u >> 16);
}
__device__ inline float bf2f(unsigned short h) {
    return __uint_as_float((unsigned int)h << 16);
}

// ---------------------------------------------------------------------------
// Zero the dense fp32 W-matrix accumulator (4MB), every call (atomics follow).
// ---------------------------------------------------------------------------
__global__ __launch_bounds__(1024) void k_zm(float* __restrict__ M32)
{
    M32[(size_t)blockIdx.x * 1024 + threadIdx.x] = 0.f;
}

// ---------------------------------------------------------------------------
// CSR build (by dst), single block: ptr/pk (lmax) + degrees + dense W scatter:
// M32[dst][src] += relu(w)  (fp32 atomics; duplicates sum correctly).
// ---------------------------------------------------------------------------
__global__ __launch_bounds__(1024) void k_csr(
    const int* __restrict__ ei, const float* __restrict__ ew,
    int* __restrict__ ptr_g, float* __restrict__ dgr_g,
    float* __restrict__ dgl_g, int2* __restrict__ packed,
    float* __restrict__ M32)
{
    __shared__ int   cnt[NNODE];
    __shared__ float dgr[NNODE];
    __shared__ float dgl[NNODE];
    __shared__ int   s[NNODE];
    __shared__ int   base[NNODE];
    const int t = threadIdx.x;

    cnt[t] = 0; dgr[t] = 0.f; dgl[t] = 0.f;

    int es[16], ed[16];
    float w[16];
#pragma unroll
    for (int i = 0; i < 16; ++i) {
        const int e = i * 1024 + t;
        es[i] = ei[e];
        ed[i] = ei[EG + e];
        w[i]  = ew[e];
    }
    __syncthreads();
#pragma unroll
    for (int i = 0; i < 16; ++i) {
        atomicAdd(&cnt[ed[i]], 1);
        atomicAdd(&dgr[es[i]], w[i]);
        atomicAdd(&dgl[es[i]], fmaxf(w[i], 0.f));
        atomicAdd(&M32[(size_t)ed[i] * 1024 + es[i]], fmaxf(w[i], 0.f));
    }
    __syncthreads();
    dgr_g[t] = dgr[t];
    dgl_g[t] = dgl[t];

    const int v = cnt[t];
    s[t] = v;
    __syncthreads();
    for (int o = 1; o < 1024; o <<= 1) {
        const int a = (t >= o) ? s[t - o] : 0;
        __syncthreads();
        s[t] += a;
        __syncthreads();
    }
    const int excl = s[t] - v;
    ptr_g[t] = excl;
    base[t]  = excl;
    if (t == 1023) ptr_g[1024] = s[1023];
    __syncthreads();

#pragma unroll
    for (int i = 0; i < 16; ++i) {
        const int p = atomicAdd(&base[ed[i]], 1);
        packed[p] = make_int2(__float_as_int(w[i]), es[i]);
    }
}

// Convert dense W fp32 -> bf16 (A-operand of the prop GEMM).
__global__ __launch_bounds__(256) void k_cvt_m(
    const float* __restrict__ M32, unsigned short* __restrict__ M16)
{
    const int i = blockIdx.x * 256 + threadIdx.x;   // 16B group
    const f32x4 v = ((const f32x4*)M32)[i];
    u16x4 o;
    o[0] = f2bf(v[0]); o[1] = f2bf(v[1]); o[2] = f2bf(v[2]); o[3] = f2bf(v[3]);
    *(u16x4*)(M16 + (size_t)i * 4) = o;
}

// ---------------------------------------------------------------------------
// Transpose x -> xB[g][f=64][k=1024] bf16, XOR-swizzled 16B chunks
// (chunk c at short-offset f*1024 + ((c ^ (f&7))*8)); also emit tcat slice 0.
// Block = (graph, 64-node span). LDS tile [64 f][66 n] u16.
// ---------------------------------------------------------------------------
__global__ __launch_bounds__(256) void k_xpose(
    const float* __restrict__ x, unsigned short* __restrict__ xB,
    unsigned short* __restrict__ tcat)
{
    __shared__ unsigned short tile[64 * 66];
    const int t = threadIdx.x;
    const int g = blockIdx.x >> 4;
    const int sp = blockIdx.x & 15;      // 64-node span
    const int n0 = sp * 64;

    const float* xg = x + (size_t)g * (NNODE * F_IN);
#pragma unroll
    for (int it = 0; it < 4; ++it) {
        const int nl = it * 16 + (t >> 4);           // 0..63
        const int f  = (t & 15) * 4;
        const f32x4 v = *(const f32x4*)(xg + (size_t)(n0 + nl) * 64 + f);
        u16x4 o;
        o[0] = f2bf(v[0]); o[1] = f2bf(v[1]); o[2] = f2bf(v[2]); o[3] = f2bf(v[3]);
        *(u16x4*)(tcat + ((size_t)(g * 1024 + n0 + nl)) * 192 + f) = o;
#pragma unroll
        for (int j = 0; j < 4; ++j) tile[(f + j) * 66 + nl] = o[j];
    }
    __syncthreads();

    unsigned short* xg2 = xB + (size_t)g * 65536;
#pragma unroll
    for (int it = 0; it < 2; ++it) {
        const int f  = t & 63;
        const int cL = (t >> 6) + it * 4;            // 0..7 chunk in span
        u16x8 v;
#pragma unroll
        for (int j = 0; j < 8; ++j) v[j] = tile[f * 66 + cL * 8 + j];
        const int c = sp * 8 + cL;                   // global chunk 0..127
        *(u16x8*)(xg2 + f * 1024 + ((c ^ (f & 7)) << 3)) = v;
    }
}

// ---------------------------------------------------------------------------
// Fused pass kernel. Block 0: lmax power-iteration chunk (25 iters per pass;
// pass 2 finalizes Rayleigh -> scal). Blocks 1..256: dense MFMA prop for one
// (graph, 512-node half): agg = M16 @ in_b; y = deg.*in - agg (diag in fp32
// path). PASS 1: in = x (fp32 diag), stages xB, writes tcat slice1 + y1B.
// PASS 2: in = y1 (bf16 diag from tcat), stages y1B, writes tcat slice2.
// ---------------------------------------------------------------------------
template<int PASS>
__global__ __launch_bounds__(1024) void k_pass(
    const float* __restrict__ x, const unsigned short* __restrict__ M16,
    const unsigned short* __restrict__ stageSrc,
    const int2* __restrict__ pk_raw, const int* __restrict__ ptrg,
    const float* __restrict__ dgr, const float* __restrict__ dgl,
    float* __restrict__ vstate, float* __restrict__ scal,
    unsigned short* __restrict__ tcat, unsigned short* __restrict__ y1B)
{
    __shared__ __align__(16) char smem[131072];
    const int t = threadIdx.x;

    if (blockIdx.x == 0) {
        // ---------------- lambda_max partial power iteration ----------------
        float* vA  = (float*)smem;
        float* vB  = vA + 1024;
        float* red = vB + 1024;
        const int it0 = (PASS == 1) ? 0 : 25;
        const int it1 = (PASS == 1) ? 25 : 50;

        const int p0 = ptrg[t], p1 = ptrg[t + 1];
        float w[RMAX];
        int src[RMAX];
#pragma unroll
        for (int i = 0; i < RMAX; ++i) {
            if (p0 + i < p1) {
                const int2 e = pk_raw[p0 + i];
                w[i] = __int_as_float(e.x);
                src[i] = e.y;
            } else {
                w[i] = 0.f;
                src[i] = 0;
            }
        }
        const int tp0 = p0 + RMAX;
        const float dgv = dgr[t];

        vA[t] = (PASS == 1) ? 0.03125f : vstate[t];
        __syncthreads();

        float* cur = vA;
        float* nxt = vB;

        for (int it = it0; it < it1; ++it) {
            float u = dgv * cur[t];
#pragma unroll
            for (int i = 0; i < RMAX; ++i) u -= w[i] * cur[src[i]];
            for (int p = tp0; p < p1; ++p) {
                const int2 e = pk_raw[p];
                u -= __int_as_float(e.x) * cur[e.y];
            }
            if ((it % NORM_EVERY) == NORM_EVERY - 1) {
                float sr = u * u;
#pragma unroll
                for (int o = 32; o > 0; o >>= 1) sr += __shfl_down(sr, o, 64);
                if ((t & 63) == 0) red[t >> 6] = sr;
                __syncthreads();
                if (t < 64) {
                    float xs2 = (t < 16) ? red[t] : 0.f;
#pragma unroll
                    for (int o = 8; o > 0; o >>= 1) xs2 += __shfl_down(xs2, o, 64);
                    if (t == 0) red[16] = 1.0f / (sqrtf(xs2) + 1e-12f);
                }
                __syncthreads();
                nxt[t] = u * red[16];
            } else {
                nxt[t] = u;
            }
            __syncthreads();
            float* tmp = cur; cur = nxt; nxt = tmp;
        }

        if (PASS == 1) {
            vstate[t] = cur[t];
            return;
        }
        // final matvec + Rayleigh quotient
        float u = dgv * cur[t];
#pragma unroll
        for (int i = 0; i < RMAX; ++i) u -= w[i] * cur[src[i]];
        for (int p = tp0; p < p1; ++p) {
            const int2 e = pk_raw[p];
            u -= __int_as_float(e.x) * cur[e.y];
        }
        float sr = cur[t] * u;
#pragma unroll
        for (int o = 32; o > 0; o >>= 1) sr += __shfl_down(sr, o, 64);
        if ((t & 63) == 0) red[t >> 6] = sr;
        __syncthreads();
        if (t == 0) {
            float lm = 0.f;
            for (int i = 0; i < 16; ++i) lm += red[i];
            scal[0] = lm;
            scal[1] = 2.0f / lm;
        }
        return;
    }

    // ---------------- dense MFMA prop ----------------
    const int bb = blockIdx.x - 1;       // 0..255
    const int g  = bb >> 1;              // graph
    const int nb = (bb & 1) << 9;        // node base 0 / 512

    // stage this graph's B operand (128KB linear copy; layout pre-swizzled)
    {
        const f32x4* src2 = (const f32x4*)(stageSrc + (size_t)g * 65536);
        f32x4* dst = (f32x4*)smem;
        for (int i = t; i < 8192; i += 1024) dst[i] = src2[i];
    }
    __syncthreads();

    const int lane = t & 63;
    const int w    = t >> 6;             // wave 0..15 -> 32 node rows each
    const int l15  = lane & 15;
    const int l4   = lane >> 4;

    f32x4 acc[2][4];
#pragma unroll
    for (int rt = 0; rt < 2; ++rt)
#pragma unroll
        for (int ft = 0; ft < 4; ++ft) acc[rt][ft] = (f32x4)(0.f);

    const unsigned short* ta =
        M16 + (size_t)(nb + w * 32 + l15) * 1024 + l4 * 8;
    bf16x8 a0 = *(const bf16x8*)(ta);
    bf16x8 a1 = *(const bf16x8*)(ta + 16 * 1024);

    for (int ks = 0; ks < 32; ++ks) {
        bf16x8 na0, na1;
        if (ks < 31) {
            na0 = *(const bf16x8*)(ta + (ks + 1) * 32);
            na1 = *(const bf16x8*)(ta + 16 * 1024 + (ks + 1) * 32);
        }
#pragma unroll
        for (int ft = 0; ft < 4; ++ft) {
            const int row = ft * 16 + l15;
            const bf16x8 bv = *(const bf16x8*)(
                smem + row * 2048 + (((ks * 4 + l4) ^ (row & 7)) << 4));
            acc[0][ft] = __builtin_amdgcn_mfma_f32_16x16x32_bf16(
                a0, bv, acc[0][ft], 0, 0, 0);
            acc[1][ft] = __builtin_amdgcn_mfma_f32_16x16x32_bf16(
                a1, bv, acc[1][ft], 0, 0, 0);
        }
        a0 = na0; a1 = na1;
    }
    __syncthreads();   // B staging dead (pass1 reuses smem for bounce)

    unsigned short* hs = (unsigned short*)smem;
#pragma unroll
    for (int rt = 0; rt < 2; ++rt) {
#pragma unroll
        for (int reg = 0; reg < 4; ++reg) {
            const int nl = w * 32 + rt * 16 + l4 * 4 + reg;   // 0..511
            const int node = nb + nl;
            const float dg = dgl[node];
#pragma unroll
            for (int ft = 0; ft < 4; ++ft) {
                const int f = ft * 16 + l15;
                float xv;
                if (PASS == 1)
                    xv = x[(size_t)g * 65536 + (size_t)node * 64 + f];
                else
                    xv = bf2f(tcat[((size_t)(g * 1024 + node)) * 192 + 64 + f]);
                const float y = dg * xv - acc[rt][ft][reg];
                tcat[((size_t)(g * 1024 + node)) * 192 + PASS * 64 + f] =
                    f2bf(y);
                if (PASS == 1) hs[nl * 66 + f] = f2bf(y);
            }
        }
    }

    if (PASS == 1) {
        __syncthreads();
        unsigned short* yg = y1B + (size_t)g * 65536;
#pragma unroll
        for (int it2 = 0; it2 < 4; ++it2) {
            const int idx = it2 * 1024 + t;
            const int f = idx & 63, cL = idx >> 6;    // cL 0..63
            u16x8 v;
#pragma unroll
            for (int j = 0; j < 8; ++j) v[j] = hs[(cL * 8 + j) * 66 + f];
            const int c = (nb >> 3) + cL;
            *(u16x8*)(yg + f * 1024 + ((c ^ (f & 7)) << 3)) = v;
        }
    }
}

// ---------------------------------------------------------------------------
// Weight conversion WITH lambda-scale folding (after lmax):
//   h = x(W0-W1+W2) + y1*s(W1-4W2) + y2*2s^2*W2,  s = 2/lmax.
// ---------------------------------------------------------------------------
__global__ __launch_bounds__(256) void k_cvtw(
    const float* __restrict__ chebW, const float* __restrict__ convW,
    const float* __restrict__ scal,
    unsigned short* __restrict__ wcatT, unsigned short* __restrict__ cvw)
{
    const int i = blockIdx.x * 256 + threadIdx.x;
    const float s = scal[1];
    if (i < 24576) {
        const int n = i / 192, kk = i % 192;
        const int k = kk & 63;
        const float w0 = chebW[k * 128 + n];
        const float w1 = chebW[8192 + k * 128 + n];
        const float w2 = chebW[16384 + k * 128 + n];
        float val;
        if (kk < 64)       val = w0 - w1 + w2;
        else if (kk < 128) val = s * (w1 - 4.f * w2);
        else               val = 2.f * s * s * w2;
        wcatT[i] = f2bf(val);
    }
    const int j = i - 24576;
    if (j >= 0 && j < 8192) cvw[j] = f2bf(convW[j]);
}

// ---------------------------------------------------------------------------
// bf16 MFMA fused cheb-GEMM + conv1d. Output bf16. (unchanged, proven)
// ---------------------------------------------------------------------------
__global__ __launch_bounds__(256) void k_cheb_mfma(
    const unsigned short* __restrict__ tcat,
    const unsigned short* __restrict__ wcatT,
    const unsigned short* __restrict__ cvw,
    const float* __restrict__ chebB, const float* __restrict__ convB,
    unsigned short* __restrict__ cout)
{
    __shared__ __align__(16) char smem[49152];
    __shared__ float cb_s[HID];
    __shared__ float cvb_s[C1];

    const int t    = threadIdx.x;
    const int lane = t & 63;
    const int wid  = t >> 6;
    const int l15  = lane & 15;
    const int l4   = lane >> 4;
    const int rbase = blockIdx.x * 128;
    const int bb = rbase >> 10;
    const int n0 = rbase & 1023;

    if (t < HID) cb_s[t] = chebB[t];
    if (t < C1)  cvb_s[t] = convB[t];

    for (int it = 0; it < 12; ++it) {
        const int gslot = it * 256 + t;
        const int n = gslot / 24, q = gslot % 24;
        const bf16x8 v = *(const bf16x8*)(wcatT + n * 192 + q * 8);
        *(bf16x8*)(smem + n * 384 + ((q ^ (n & 7)) << 4)) = v;
    }
    __syncthreads();

    const int rw = rbase + wid * 32;
    f32x4 acc[2][8];
#pragma unroll
    for (int m = 0; m < 2; ++m)
#pragma unroll
        for (int n = 0; n < 8; ++n) acc[m][n] = (f32x4)(0.f);

    const unsigned short* ta = tcat + (size_t)(rw + l15) * 192 + l4 * 8;
    bf16x8 a0 = *(const bf16x8*)(ta);
    bf16x8 a1 = *(const bf16x8*)(ta + 16 * 192);

#pragma unroll
    for (int ks = 0; ks < 6; ++ks) {
        bf16x8 na0, na1;
        if (ks < 5) {
            na0 = *(const bf16x8*)(ta + (ks + 1) * 32);
            na1 = *(const bf16x8*)(ta + 16 * 192 + (ks + 1) * 32);
        }
        const int kb = ks * 4 + l4;
#pragma unroll
        for (int nb = 0; nb < 8; ++nb) {
            const int n = nb * 16 + l15;
            const bf16x8 bv =
                *(const bf16x8*)(smem + n * 384 + ((kb ^ (n & 7)) << 4));
            acc[0][nb] = __builtin_amdgcn_mfma_f32_16x16x32_bf16(
                a0, bv, acc[0][nb], 0, 0, 0);
            acc[1][nb] = __builtin_amdgcn_mfma_f32_16x16x32_bf16(
                a1, bv, acc[1][nb], 0, 0, 0);
        }
        a0 = na0; a1 = na1;
    }
    __syncthreads();

#pragma unroll
    for (int mf = 0; mf < 2; ++mf)
#pragma unroll
        for (int nb = 0; nb < 8; ++nb) {
            const int c = nb * 16 + l15;
            const int slot = c >> 3;
            const float cb = cb_s[c];
#pragma unroll
            for (int reg = 0; reg < 4; ++reg) {
                const int node = wid * 32 + mf * 16 + l4 * 4 + reg;
                *(unsigned short*)(smem + node * 256 +
                                   ((slot ^ (node & 7)) << 4) + (c & 7) * 2) =
                    f2bf(acc[mf][nb][reg] + cb);
            }
        }
    for (int it = 0; it < 4; ++it) {
        const int gslot = it * 256 + t;
        const int c1i = gslot >> 4, q = gslot & 15;
        const bf16x8 v = *(const bf16x8*)(cvw + c1i * 128 + q * 8);
        *(bf16x8*)(smem + 32768 + c1i * 256 + ((q ^ (c1i & 7)) << 4)) = v;
    }
    __syncthreads();

    f32x4 acc2[8];
#pragma unroll
    for (int n = 0; n < 8; ++n) acc2[n] = (f32x4)(0.f);

#pragma unroll
    for (int ks = 0; ks < 4; ++ks) {
        const int kb = ks * 4 + l4;
        const int c1a = wid * 16 + l15;
        const bf16x8 av = *(const bf16x8*)(smem + 32768 + c1a * 256 +
                                           ((kb ^ (c1a & 7)) << 4));
#pragma unroll
        for (int nb = 0; nb < 8; ++nb) {
            const int node = nb * 16 + l15;
            const bf16x8 bv =
                *(const bf16x8*)(smem + node * 256 + ((kb ^ (node & 7)) << 4));
            acc2[nb] = __builtin_amdgcn_mfma_f32_16x16x32_bf16(
                av, bv, acc2[nb], 0, 0, 0);
        }
    }

#pragma unroll
    for (int nb = 0; nb < 8; ++nb) {
        const int ng = n0 + nb * 16 + l15;
#pragma unroll
        for (int reg = 0; reg < 4; ++reg) {
            const int c1i = wid * 16 + l4 * 4 + reg;
            cout[(size_t)bb * (C1 * NNODE) + (size_t)c1i * NNODE + ng] =
                f2bf(fmaxf(acc2[nb][reg] + cvb_s[c1i], 0.f));
        }
    }
}

// ---------------------------------------------------------------------------
// fc1 partials (K-split over 256-col chunks), bf16 input; reduce; head.
// ---------------------------------------------------------------------------
__global__ __launch_bounds__(256) void k_fc1(
    const unsigned short* __restrict__ cf, const float* __restrict__ W,
    float* __restrict__ part)
{
    __shared__ float Wt[256 * 33];
    const int t = threadIdx.x;
    const int g = blockIdx.x;
    const int k0 = g * 256;

    for (int i = t; i < 8192; i += 256) {
        const int j = i >> 8, k = i & 255;
        Wt[k * 33 + j] = W[(size_t)j * (C1 * NNODE) + k0 + k];
    }
    __syncthreads();

    const int j = t & 31, bg = t >> 5;
    float acc[16];
#pragma unroll
    for (int i = 0; i < 16; ++i) acc[i] = 0.f;

    const unsigned short* cb = cf + (size_t)(bg * 16) * (C1 * NNODE) + k0;
    for (int k4 = 0; k4 < 64; ++k4) {
        const int kb = k4 * 4;
        const float w0 = Wt[(kb + 0) * 33 + j];
        const float w1 = Wt[(kb + 1) * 33 + j];
        const float w2 = Wt[(kb + 2) * 33 + j];
        const float w3 = Wt[(kb + 3) * 33 + j];
#pragma unroll
        for (int i = 0; i < 16; ++i) {
            const u16x4 cv = *(const u16x4*)&cb[(size_t)i * (C1 * NNODE) + kb];
            acc[i] += bf2f(cv[0]) * w0 + bf2f(cv[1]) * w1 +
                      bf2f(cv[2]) * w2 + bf2f(cv[3]) * w3;
        }
    }
#pragma unroll
    for (int i = 0; i < 16; ++i)
        part[(size_t)g * 4096 + (size_t)(bg * 16 + i) * 32 + j] = acc[i];
}

__global__ __launch_bounds__(256) void k_red(
    const float* __restrict__ part, float* __restrict__ z)
{
    const int o = blockIdx.x * 256 + threadIdx.x;
    float s = 0.f;
    for (int g = 0; g < 256; ++g) s += part[(size_t)g * 4096 + o];
    z[o] = s;
}

__global__ __launch_bounds__(128) void k_head(
    const float* __restrict__ z, const float* __restrict__ b1,
    const float* __restrict__ W2, const float* __restrict__ b2,
    float* __restrict__ outp)
{
    const int b = threadIdx.x;
    float a[32];
#pragma unroll
    for (int j = 0; j < 32; ++j) a[j] = z[b * 32 + j] + b1[j];
    float l[4];
#pragma unroll
    for (int c = 0; c < 4; ++c) {
        float s = b2[c];
#pragma unroll
        for (int j = 0; j < 32; ++j) s += W2[c * 32 + j] * a[j];
        l[c] = s;
    }
    const float m = fmaxf(fmaxf(l[0], l[1]), fmaxf(l[2], l[3]));
    const float e0 = expf(l[0] - m), e1 = expf(l[1] - m);
    const float e2 = expf(l[2] - m), e3 = expf(l[3] - m);
    const float inv = 1.f / (e0 + e1 + e2 + e3);
    outp[b * 4 + 0] = e0 * inv;
    outp[b * 4 + 1] = e1 * inv;
    outp[b * 4 + 2] = e2 * inv;
    outp[b * 4 + 3] = e3 * inv;
}

// ---------------------------------------------------------------------------
extern "C" void kernel_launch(void* const* d_in, const int* in_sizes, int n_in,
                              void* d_out, int out_size, void* d_ws, size_t ws_size,
                              hipStream_t stream)
{
    const float* x     = (const float*)d_in[0];
    const int*   ei    = (const int*)d_in[1];
    const float* ew    = (const float*)d_in[2];
    const float* chebW = (const float*)d_in[3];
    const float* chebB = (const float*)d_in[4];
    const float* convW = (const float*)d_in[5];
    const float* convB = (const float*)d_in[6];
    const float* fc1W  = (const float*)d_in[7];
    const float* fc1B  = (const float*)d_in[8];
    const float* fc2W  = (const float*)d_in[9];
    const float* fc2B  = (const float*)d_in[10];
    float* out = (float*)d_out;

    char* ws = (char*)d_ws;
    float* scal   = (float*)(ws + 0);
    float* vstate = (float*)(ws + 4096);
    char*  partb  = ws + 8192;                      // 4MB multi-use region
    int*   ptr  = (int*)(partb + 8192);
    float* dgr  = (float*)(partb + 24576);
    float* dgl  = (float*)(partb + 28672);
    int2*  pk   = (int2*)(partb + 32768);           // 128KB (raw w, src)
    unsigned short* wcatT = (unsigned short*)(partb + 327680);  // 48KB
    unsigned short* cvwB  = (unsigned short*)(partb + 393216);  // 16KB
    float* part = (float*)partb;                    // fc1 partials (after cheb)
    float* z    = (float*)(ws + 4202496);           // 64KB
    float*          M32  = (float*)(ws + 4268032);            // 4MB
    unsigned short* M16  = (unsigned short*)(ws + 8462336);   // 2MB
    unsigned short* xB   = (unsigned short*)(ws + 10559488);  // 16MB
    unsigned short* y1B  = (unsigned short*)(ws + 27336704);  // 16MB
    unsigned short* tcat = (unsigned short*)(ws + 44113920);  // 48MB
    unsigned short* cbuf = (unsigned short*)(ws + 94445568);  // 16MB

    k_zm   <<<dim3(1024), dim3(1024), 0, stream>>>(M32);
    k_csr  <<<dim3(1),    dim3(1024), 0, stream>>>(ei, ew, ptr, dgr, dgl, pk,
                                                   M32);
    k_cvt_m<<<dim3(1024), dim3(256),  0, stream>>>(M32, M16);
    k_xpose<<<dim3(2048), dim3(256),  0, stream>>>(x, xB, tcat);

    k_pass<1><<<dim3(257), dim3(1024), 0, stream>>>(
        x, M16, xB, pk, ptr, dgr, dgl, vstate, scal, tcat, y1B);
    k_pass<2><<<dim3(257), dim3(1024), 0, stream>>>(
        x, M16, y1B, pk, ptr, dgr, dgl, vstate, scal, tcat, y1B);

    k_cvtw<<<dim3(128), dim3(256), 0, stream>>>(chebW, convW, scal, wcatT, cvwB);

    k_cheb_mfma<<<dim3(BN / 128), dim3(256), 0, stream>>>(
        tcat, wcatT, cvwB, chebB, convB, cbuf);

    k_fc1<<<dim3(256), dim3(256), 0, stream>>>(cbuf, fc1W, part);
    k_red<<<dim3(16), dim3(256), 0, stream>>>(part, z);
    k_head<<<dim3(1), dim3(128), 0, stream>>>(z, fc1B, fc2W, fc2B, out);
}

// Round 11
// 314.926 us; speedup vs baseline: 1.6530x; 1.0131x over previous
//
#include <hip/hip_runtime.h>
#include <math.h>

#define BATCH 128
#define NNODE 1024
#define EG 16384
#define F_IN 64
#define HID 128
#define C1 64
#define C2 32
#define NCLS 4
#define POWER_ITERS 50
#define BN (BATCH * NNODE)
#define RMAX 28
#define NORM_EVERY 5
#define PRE 20

typedef float f32x4 __attribute__((ext_vector_type(4)));
typedef __bf16 bf16x8 __attribute__((ext_vector_type(8)));
typedef unsigned short u16x4 __attribute__((ext_vector_type(4)));

__device__ inline unsigned short f2bf(float f) {   // round-to-nearest-even
    unsigned int u = __float_as_uint(f);
    u += 0x7fffu + ((u >> 16) & 1u);
    return (unsigned short)(u >> 16);
}
__device__ inline float bf2f(unsigned short h) {
    return __uint_as_float((unsigned int)h << 16);
}

// ---------------------------------------------------------------------------
// CSR build (by dst), single block. pk {raw_w, src} for lmax;
// pk2 {relu_w, src*128} = byte offset into bf16 [node][64] rows, for prop.
// ---------------------------------------------------------------------------
__global__ __launch_bounds__(1024) void k_csr(
    const int* __restrict__ ei, const float* __restrict__ ew,
    int* __restrict__ ptr_g, float* __restrict__ dgr_g,
    float* __restrict__ dgl_g, int2* __restrict__ packed,
    int2* __restrict__ packed2)
{
    __shared__ int   cnt[NNODE];
    __shared__ float dgr[NNODE];
    __shared__ float dgl[NNODE];
    __shared__ int   s[NNODE];
    __shared__ int   base[NNODE];
    const int t = threadIdx.x;

    cnt[t] = 0; dgr[t] = 0.f; dgl[t] = 0.f;

    int es[16], ed[16];
    float w[16];
#pragma unroll
    for (int i = 0; i < 16; ++i) {
        const int e = i * 1024 + t;
        es[i] = ei[e];
        ed[i] = ei[EG + e];
        w[i]  = ew[e];
    }
    __syncthreads();
#pragma unroll
    for (int i = 0; i < 16; ++i) {
        atomicAdd(&cnt[ed[i]], 1);
        atomicAdd(&dgr[es[i]], w[i]);
        atomicAdd(&dgl[es[i]], fmaxf(w[i], 0.f));
    }
    __syncthreads();
    dgr_g[t] = dgr[t];
    dgl_g[t] = dgl[t];

    const int v = cnt[t];
    s[t] = v;
    __syncthreads();
    for (int o = 1; o < 1024; o <<= 1) {
        const int a = (t >= o) ? s[t - o] : 0;
        __syncthreads();
        s[t] += a;
        __syncthreads();
    }
    const int excl = s[t] - v;
    ptr_g[t] = excl;
    base[t]  = excl;
    if (t == 1023) ptr_g[1024] = s[1023];
    __syncthreads();

#pragma unroll
    for (int i = 0; i < 16; ++i) {
        const int p = atomicAdd(&base[ed[i]], 1);
        packed[p]  = make_int2(__float_as_int(w[i]), es[i]);
        packed2[p] = make_int2(__float_as_int(fmaxf(w[i], 0.f)), es[i] << 7);
    }
}

// ---------------------------------------------------------------------------
// x -> xb16 [BN][64] bf16 (gather source) + tcat slice 0.
// ---------------------------------------------------------------------------
__global__ __launch_bounds__(256) void k_xb(
    const float* __restrict__ x, unsigned short* __restrict__ xb16,
    unsigned short* __restrict__ tcat)
{
    const int i = blockIdx.x * 256 + threadIdx.x;   // f32x4 index
    const f32x4 v = ((const f32x4*)x)[i];
    u16x4 o;
    o[0] = f2bf(v[0]); o[1] = f2bf(v[1]); o[2] = f2bf(v[2]); o[3] = f2bf(v[3]);
    *(u16x4*)(xb16 + (size_t)i * 4) = o;
    const int node = i >> 4;
    const int fb = (i & 15) * 4;
    *(u16x4*)(tcat + (size_t)node * 192 + fb) = o;
}

// ---------------------------------------------------------------------------
// Fused pass kernel. Block 0: lmax power-iteration half (25 iters; pass 2
// finalizes Rayleigh -> scal). Blocks 1..8192: y = dgl.*in - agg(in), one
// wave per node. Edge records preloaded into SGPRs (PRE slots, clamped,
// branchless); all PRE bf16 gathers issued back-to-back; rare deg>PRE tail.
// PASS 1: gathers xb16, diag from fp32 x, writes tcat slice1 + y1b.
// PASS 2: gathers y1b,  diag from y1b,   writes tcat slice2.
// ---------------------------------------------------------------------------
template<int PASS>
__global__ __launch_bounds__(1024) void k_fused(
    const float* __restrict__ x, const unsigned short* __restrict__ gsrc,
    const int2* __restrict__ pk_raw, const int2* __restrict__ pk2,
    const int* __restrict__ ptrg,
    const float* __restrict__ dgr, const float* __restrict__ dgl,
    float* __restrict__ vstate, float* __restrict__ scal,
    unsigned short* __restrict__ tcat, unsigned short* __restrict__ y1b)
{
    __shared__ float vA[NNODE];
    __shared__ float vB[NNODE];
    __shared__ float red[17];
    const int t = threadIdx.x;

    if (blockIdx.x == 0) {
        // ---------------- lambda_max partial power iteration ----------------
        const int it0 = (PASS == 1) ? 0 : 25;
        const int it1 = (PASS == 1) ? 25 : 50;

        const int p0 = ptrg[t], p1 = ptrg[t + 1];
        float w[RMAX];
        int src[RMAX];
#pragma unroll
        for (int i = 0; i < RMAX; ++i) {
            if (p0 + i < p1) {
                const int2 e = pk_raw[p0 + i];
                w[i] = __int_as_float(e.x);
                src[i] = e.y;
            } else {
                w[i] = 0.f;
                src[i] = 0;
            }
        }
        const int tp0 = p0 + RMAX;
        const float dgv = dgr[t];

        vA[t] = (PASS == 1) ? 0.03125f : vstate[t];
        __syncthreads();

        float* cur = vA;
        float* nxt = vB;

        for (int it = it0; it < it1; ++it) {
            float u = dgv * cur[t];
#pragma unroll
            for (int i = 0; i < RMAX; ++i) u -= w[i] * cur[src[i]];
            for (int p = tp0; p < p1; ++p) {
                const int2 e = pk_raw[p];
                u -= __int_as_float(e.x) * cur[e.y];
            }
            if ((it % NORM_EVERY) == NORM_EVERY - 1) {
                float sr = u * u;
#pragma unroll
                for (int o = 32; o > 0; o >>= 1) sr += __shfl_down(sr, o, 64);
                if ((t & 63) == 0) red[t >> 6] = sr;
                __syncthreads();
                if (t < 64) {
                    float xs2 = (t < 16) ? red[t] : 0.f;
#pragma unroll
                    for (int o = 8; o > 0; o >>= 1) xs2 += __shfl_down(xs2, o, 64);
                    if (t == 0) red[16] = 1.0f / (sqrtf(xs2) + 1e-12f);
                }
                __syncthreads();
                nxt[t] = u * red[16];
            } else {
                nxt[t] = u;
            }
            __syncthreads();
            float* tmp = cur; cur = nxt; nxt = tmp;
        }

        if (PASS == 1) {
            vstate[t] = cur[t];
            return;
        }
        float u = dgv * cur[t];
#pragma unroll
        for (int i = 0; i < RMAX; ++i) u -= w[i] * cur[src[i]];
        for (int p = tp0; p < p1; ++p) {
            const int2 e = pk_raw[p];
            u -= __int_as_float(e.x) * cur[e.y];
        }
        float sr = cur[t] * u;
#pragma unroll
        for (int o = 32; o > 0; o >>= 1) sr += __shfl_down(sr, o, 64);
        if ((t & 63) == 0) red[t >> 6] = sr;
        __syncthreads();
        if (t == 0) {
            float lm = 0.f;
            for (int i = 0; i < 16; ++i) lm += red[i];
            scal[0] = lm;
            scal[1] = 2.0f / lm;
        }
        return;
    }

    // ---------------- prop path: one wave per node ----------------
    const int b1   = blockIdx.x - 1;
    const int bid  = ((b1 & 7) << 10) + (b1 >> 3);     // XCD swizzle over 8192
    const int lane = t & 63;
    const int gnode = __builtin_amdgcn_readfirstlane(bid * 16 + (t >> 6));
    const int b = gnode >> 10, d = gnode & 1023;

    const int p0 = __builtin_amdgcn_readfirstlane(ptrg[d]);
    const int p1 = __builtin_amdgcn_readfirstlane(ptrg[d + 1]);
    const char* gb = (const char*)(gsrc + (size_t)b * 65536);

    // preload PRE edge records (uniform -> SGPRs), branchless clamped index
    float ew_r[PRE];
    unsigned off_r[PRE];
#pragma unroll
    for (int i = 0; i < PRE; ++i) {
        int idx = p0 + i;
        idx = (idx < p1) ? idx : (p1 - 1);
        idx = (idx < EG) ? idx : (EG - 1);
        idx = (idx > 0) ? idx : 0;
        const int2 e = pk2[idx];
        const bool valid = (p0 + i < p1);
        ew_r[i]  = valid ? __int_as_float(e.x) : 0.f;
        off_r[i] = valid ? (unsigned)e.y : 0u;
    }

    // issue all gathers, then consume (2 accumulators for ILP)
    float vv[PRE];
#pragma unroll
    for (int i = 0; i < PRE; ++i)
        vv[i] = bf2f(*(const unsigned short*)(gb + off_r[i] + (lane << 1)));

    float acc0 = 0.f, acc1 = 0.f;
#pragma unroll
    for (int i = 0; i < PRE; i += 2) {
        acc0 += ew_r[i] * vv[i];
        acc1 += ew_r[i + 1] * vv[i + 1];
    }
    float acc = acc0 + acc1;

    for (int p = p0 + PRE; p < p1; ++p) {            // rare tail (deg > PRE)
        const int2 e = pk2[p];
        acc += __int_as_float(e.x) *
               bf2f(*(const unsigned short*)(gb + (unsigned)e.y + (lane << 1)));
    }

    float xv;
    if (PASS == 1) xv = x[(size_t)gnode * 64 + lane];
    else           xv = bf2f(gsrc[(size_t)gnode * 64 + lane]);
    const float y = dgl[d] * xv - acc;
    tcat[(size_t)gnode * 192 + PASS * 64 + lane] = f2bf(y);
    if (PASS == 1) y1b[(size_t)gnode * 64 + lane] = f2bf(y);
}

// ---------------------------------------------------------------------------
// Weight conversion WITH lambda-scale folding (after lmax):
//   h = x(W0-W1+W2) + y1*s(W1-4W2) + y2*2s^2*W2,  s = 2/lmax.
// ---------------------------------------------------------------------------
__global__ __launch_bounds__(256) void k_cvtw(
    const float* __restrict__ chebW, const float* __restrict__ convW,
    const float* __restrict__ scal,
    unsigned short* __restrict__ wcatT, unsigned short* __restrict__ cvw)
{
    const int i = blockIdx.x * 256 + threadIdx.x;
    const float s = scal[1];
    if (i < 24576) {
        const int n = i / 192, kk = i % 192;
        const int k = kk & 63;
        const float w0 = chebW[k * 128 + n];
        const float w1 = chebW[8192 + k * 128 + n];
        const float w2 = chebW[16384 + k * 128 + n];
        float val;
        if (kk < 64)       val = w0 - w1 + w2;
        else if (kk < 128) val = s * (w1 - 4.f * w2);
        else               val = 2.f * s * s * w2;
        wcatT[i] = f2bf(val);
    }
    const int j = i - 24576;
    if (j >= 0 && j < 8192) cvw[j] = f2bf(convW[j]);
}

// ---------------------------------------------------------------------------
// bf16 MFMA fused cheb-GEMM + conv1d. Output bf16. (unchanged, proven)
// ---------------------------------------------------------------------------
__global__ __launch_bounds__(256) void k_cheb_mfma(
    const unsigned short* __restrict__ tcat,
    const unsigned short* __restrict__ wcatT,
    const unsigned short* __restrict__ cvw,
    const float* __restrict__ chebB, const float* __restrict__ convB,
    unsigned short* __restrict__ cout)
{
    __shared__ __align__(16) char smem[49152];
    __shared__ float cb_s[HID];
    __shared__ float cvb_s[C1];

    const int t    = threadIdx.x;
    const int lane = t & 63;
    const int wid  = t >> 6;
    const int l15  = lane & 15;
    const int l4   = lane >> 4;
    const int rbase = blockIdx.x * 128;
    const int bb = rbase >> 10;
    const int n0 = rbase & 1023;

    if (t < HID) cb_s[t] = chebB[t];
    if (t < C1)  cvb_s[t] = convB[t];

    for (int it = 0; it < 12; ++it) {
        const int gslot = it * 256 + t;
        const int n = gslot / 24, q = gslot % 24;
        const bf16x8 v = *(const bf16x8*)(wcatT + n * 192 + q * 8);
        *(bf16x8*)(smem + n * 384 + ((q ^ (n & 7)) << 4)) = v;
    }
    __syncthreads();

    const int rw = rbase + wid * 32;
    f32x4 acc[2][8];
#pragma unroll
    for (int m = 0; m < 2; ++m)
#pragma unroll
        for (int n = 0; n < 8; ++n) acc[m][n] = (f32x4)(0.f);

    const unsigned short* ta = tcat + (size_t)(rw + l15) * 192 + l4 * 8;
    bf16x8 a0 = *(const bf16x8*)(ta);
    bf16x8 a1 = *(const bf16x8*)(ta + 16 * 192);

#pragma unroll
    for (int ks = 0; ks < 6; ++ks) {
        bf16x8 na0, na1;
        if (ks < 5) {
            na0 = *(const bf16x8*)(ta + (ks + 1) * 32);
            na1 = *(const bf16x8*)(ta + 16 * 192 + (ks + 1) * 32);
        }
        const int kb = ks * 4 + l4;
#pragma unroll
        for (int nb = 0; nb < 8; ++nb) {
            const int n = nb * 16 + l15;
            const bf16x8 bv =
                *(const bf16x8*)(smem + n * 384 + ((kb ^ (n & 7)) << 4));
            acc[0][nb] = __builtin_amdgcn_mfma_f32_16x16x32_bf16(
                a0, bv, acc[0][nb], 0, 0, 0);
            acc[1][nb] = __builtin_amdgcn_mfma_f32_16x16x32_bf16(
                a1, bv, acc[1][nb], 0, 0, 0);
        }
        a0 = na0; a1 = na1;
    }
    __syncthreads();

#pragma unroll
    for (int mf = 0; mf < 2; ++mf)
#pragma unroll
        for (int nb = 0; nb < 8; ++nb) {
            const int c = nb * 16 + l15;
            const int slot = c >> 3;
            const float cb = cb_s[c];
#pragma unroll
            for (int reg = 0; reg < 4; ++reg) {
                const int node = wid * 32 + mf * 16 + l4 * 4 + reg;
                *(unsigned short*)(smem + node * 256 +
                                   ((slot ^ (node & 7)) << 4) + (c & 7) * 2) =
                    f2bf(acc[mf][nb][reg] + cb);
            }
        }
    for (int it = 0; it < 4; ++it) {
        const int gslot = it * 256 + t;
        const int c1i = gslot >> 4, q = gslot & 15;
        const bf16x8 v = *(const bf16x8*)(cvw + c1i * 128 + q * 8);
        *(bf16x8*)(smem + 32768 + c1i * 256 + ((q ^ (c1i & 7)) << 4)) = v;
    }
    __syncthreads();

    f32x4 acc2[8];
#pragma unroll
    for (int n = 0; n < 8; ++n) acc2[n] = (f32x4)(0.f);

#pragma unroll
    for (int ks = 0; ks < 4; ++ks) {
        const int kb = ks * 4 + l4;
        const int c1a = wid * 16 + l15;
        const bf16x8 av = *(const bf16x8*)(smem + 32768 + c1a * 256 +
                                           ((kb ^ (c1a & 7)) << 4));
#pragma unroll
        for (int nb = 0; nb < 8; ++nb) {
            const int node = nb * 16 + l15;
            const bf16x8 bv =
                *(const bf16x8*)(smem + node * 256 + ((kb ^ (node & 7)) << 4));
            acc2[nb] = __builtin_amdgcn_mfma_f32_16x16x32_bf16(
                av, bv, acc2[nb], 0, 0, 0);
        }
    }

#pragma unroll
    for (int nb = 0; nb < 8; ++nb) {
        const int ng = n0 + nb * 16 + l15;
#pragma unroll
        for (int reg = 0; reg < 4; ++reg) {
            const int c1i = wid * 16 + l4 * 4 + reg;
            cout[(size_t)bb * (C1 * NNODE) + (size_t)c1i * NNODE + ng] =
                f2bf(fmaxf(acc2[nb][reg] + cvb_s[c1i], 0.f));
        }
    }
}

// ---------------------------------------------------------------------------
// fc1 partials (K-split over 256-col chunks), bf16 input; reduce; head.
// ---------------------------------------------------------------------------
__global__ __launch_bounds__(256) void k_fc1(
    const unsigned short* __restrict__ cf, const float* __restrict__ W,
    float* __restrict__ part)
{
    __shared__ float Wt[256 * 33];
    const int t = threadIdx.x;
    const int g = blockIdx.x;
    const int k0 = g * 256;

    for (int i = t; i < 8192; i += 256) {
        const int j = i >> 8, k = i & 255;
        Wt[k * 33 + j] = W[(size_t)j * (C1 * NNODE) + k0 + k];
    }
    __syncthreads();

    const int j = t & 31, bg = t >> 5;
    float acc[16];
#pragma unroll
    for (int i = 0; i < 16; ++i) acc[i] = 0.f;

    const unsigned short* cb = cf + (size_t)(bg * 16) * (C1 * NNODE) + k0;
    for (int k4 = 0; k4 < 64; ++k4) {
        const int kb = k4 * 4;
        const float w0 = Wt[(kb + 0) * 33 + j];
        const float w1 = Wt[(kb + 1) * 33 + j];
        const float w2 = Wt[(kb + 2) * 33 + j];
        const float w3 = Wt[(kb + 3) * 33 + j];
#pragma unroll
        for (int i = 0; i < 16; ++i) {
            const u16x4 cv = *(const u16x4*)&cb[(size_t)i * (C1 * NNODE) + kb];
            acc[i] += bf2f(cv[0]) * w0 + bf2f(cv[1]) * w1 +
                      bf2f(cv[2]) * w2 + bf2f(cv[3]) * w3;
        }
    }
#pragma unroll
    for (int i = 0; i < 16; ++i)
        part[(size_t)g * 4096 + (size_t)(bg * 16 + i) * 32 + j] = acc[i];
}

__global__ __launch_bounds__(256) void k_red(
    const float* __restrict__ part, float* __restrict__ z)
{
    const int o = blockIdx.x * 256 + threadIdx.x;
    float s = 0.f;
    for (int g = 0; g < 256; ++g) s += part[(size_t)g * 4096 + o];
    z[o] = s;
}

__global__ __launch_bounds__(128) void k_head(
    const float* __restrict__ z, const float* __restrict__ b1,
    const float* __restrict__ W2, const float* __restrict__ b2,
    float* __restrict__ outp)
{
    const int b = threadIdx.x;
    float a[32];
#pragma unroll
    for (int j = 0; j < 32; ++j) a[j] = z[b * 32 + j] + b1[j];
    float l[4];
#pragma unroll
    for (int c = 0; c < 4; ++c) {
        float s = b2[c];
#pragma unroll
        for (int j = 0; j < 32; ++j) s += W2[c * 32 + j] * a[j];
        l[c] = s;
    }
    const float m = fmaxf(fmaxf(l[0], l[1]), fmaxf(l[2], l[3]));
    const float e0 = expf(l[0] - m), e1 = expf(l[1] - m);
    const float e2 = expf(l[2] - m), e3 = expf(l[3] - m);
    const float inv = 1.f / (e0 + e1 + e2 + e3);
    outp[b * 4 + 0] = e0 * inv;
    outp[b * 4 + 1] = e1 * inv;
    outp[b * 4 + 2] = e2 * inv;
    outp[b * 4 + 3] = e3 * inv;
}

// ---------------------------------------------------------------------------
extern "C" void kernel_launch(void* const* d_in, const int* in_sizes, int n_in,
                              void* d_out, int out_size, void* d_ws, size_t ws_size,
                              hipStream_t stream)
{
    const float* x     = (const float*)d_in[0];
    const int*   ei    = (const int*)d_in[1];
    const float* ew    = (const float*)d_in[2];
    const float* chebW = (const float*)d_in[3];
    const float* chebB = (const float*)d_in[4];
    const float* convW = (const float*)d_in[5];
    const float* convB = (const float*)d_in[6];
    const float* fc1W  = (const float*)d_in[7];
    const float* fc1B  = (const float*)d_in[8];
    const float* fc2W  = (const float*)d_in[9];
    const float* fc2B  = (const float*)d_in[10];
    float* out = (float*)d_out;

    char* ws = (char*)d_ws;
    float* scal   = (float*)(ws + 0);
    float* vstate = (float*)(ws + 4096);
    char*  partb  = ws + 8192;                      // 4MB multi-use region
    int*   ptr  = (int*)(partb + 8192);
    float* dgr  = (float*)(partb + 16384);
    float* dgl  = (float*)(partb + 20480);
    int2*  pk   = (int2*)(partb + 24576);           // 128KB (raw w, src)
    unsigned short* wcatT = (unsigned short*)(partb + 262144);  // 48KB
    unsigned short* cvwB  = (unsigned short*)(partb + 327680);  // 16KB
    int2*  pk2  = (int2*)(partb + 458752);          // 128KB (relu w, src*128)
    float* part = (float*)partb;                    // fc1 partials (after cheb)
    float* z    = (float*)(ws + 4202496);           // 64KB
    unsigned short* xb16 = (unsigned short*)(ws + 4268032);   // 16MB
    unsigned short* y1b  = (unsigned short*)(ws + 21045248);  // 16MB
    unsigned short* tcat = (unsigned short*)(ws + 37822464);  // 48MB
    unsigned short* cbuf = (unsigned short*)(ws + 88154112);  // 16MB

    k_csr<<<dim3(1),    dim3(1024), 0, stream>>>(ei, ew, ptr, dgr, dgl, pk, pk2);
    k_xb <<<dim3(8192), dim3(256),  0, stream>>>(x, xb16, tcat);

    k_fused<1><<<dim3(8193), dim3(1024), 0, stream>>>(
        x, xb16, pk, pk2, ptr, dgr, dgl, vstate, scal, tcat, y1b);
    k_fused<2><<<dim3(8193), dim3(1024), 0, stream>>>(
        x, y1b, pk, pk2, ptr, dgr, dgl, vstate, scal, tcat, y1b);

    k_cvtw<<<dim3(128), dim3(256), 0, stream>>>(chebW, convW, scal, wcatT, cvwB);

    k_cheb_mfma<<<dim3(BN / 128), dim3(256), 0, stream>>>(
        tcat, wcatT, cvwB, chebB, convB, cbuf);

    k_fc1<<<dim3(256), dim3(256), 0, stream>>>(cbuf, fc1W, part);
    k_red<<<dim3(16), dim3(256), 0, stream>>>(part, z);
    k_head<<<dim3(1), dim3(128), 0, stream>>>(z, fc1B, fc2W, fc2B, out);
}

// Round 12
// 301.500 us; speedup vs baseline: 1.7266x; 1.0445x over previous
//
#include <hip/hip_runtime.h>
#include <math.h>

#define BATCH 128
#define NNODE 1024
#define EG 16384
#define F_IN 64
#define HID 128
#define C1 64
#define C2 32
#define NCLS 4
#define POWER_ITERS 50
#define BN (BATCH * NNODE)
#define RMAX 28
#define NORM_EVERY 5

typedef float f32x4 __attribute__((ext_vector_type(4)));
typedef __bf16 bf16x8 __attribute__((ext_vector_type(8)));
typedef unsigned short u16x4 __attribute__((ext_vector_type(4)));

__device__ inline unsigned short f2bf(float f) {   // round-to-nearest-even
    unsigned int u = __float_as_uint(f);
    u += 0x7fffu + ((u >> 16) & 1u);
    return (unsigned short)(u >> 16);
}
__device__ inline float bf2f(unsigned short h) {
    return __uint_as_float((unsigned int)h << 16);
}

// ---------------------------------------------------------------------------
// CSR build (by dst), single block. pk {raw_w, src} for lmax;
// pk2 {relu_w, src*128} = byte offset into bf16 [node][64] rows, for prop.
// ---------------------------------------------------------------------------
__global__ __launch_bounds__(1024) void k_csr(
    const int* __restrict__ ei, const float* __restrict__ ew,
    int* __restrict__ ptr_g, float* __restrict__ dgr_g,
    float* __restrict__ dgl_g, int2* __restrict__ packed,
    int2* __restrict__ packed2)
{
    __shared__ int   cnt[NNODE];
    __shared__ float dgr[NNODE];
    __shared__ float dgl[NNODE];
    __shared__ int   s[NNODE];
    __shared__ int   base[NNODE];
    const int t = threadIdx.x;

    cnt[t] = 0; dgr[t] = 0.f; dgl[t] = 0.f;

    int es[16], ed[16];
    float w[16];
#pragma unroll
    for (int i = 0; i < 16; ++i) {
        const int e = i * 1024 + t;
        es[i] = ei[e];
        ed[i] = ei[EG + e];
        w[i]  = ew[e];
    }
    __syncthreads();
#pragma unroll
    for (int i = 0; i < 16; ++i) {
        atomicAdd(&cnt[ed[i]], 1);
        atomicAdd(&dgr[es[i]], w[i]);
        atomicAdd(&dgl[es[i]], fmaxf(w[i], 0.f));
    }
    __syncthreads();
    dgr_g[t] = dgr[t];
    dgl_g[t] = dgl[t];

    const int v = cnt[t];
    s[t] = v;
    __syncthreads();
    for (int o = 1; o < 1024; o <<= 1) {
        const int a = (t >= o) ? s[t - o] : 0;
        __syncthreads();
        s[t] += a;
        __syncthreads();
    }
    const int excl = s[t] - v;
    ptr_g[t] = excl;
    base[t]  = excl;
    if (t == 1023) ptr_g[1024] = s[1023];
    __syncthreads();

#pragma unroll
    for (int i = 0; i < 16; ++i) {
        const int p = atomicAdd(&base[ed[i]], 1);
        packed[p]  = make_int2(__float_as_int(w[i]), es[i]);
        packed2[p] = make_int2(__float_as_int(fmaxf(w[i], 0.f)), es[i] << 7);
    }
}

// ---------------------------------------------------------------------------
// x -> xb16 [BN][64] bf16 (gather source) + tcat slice 0.
// ---------------------------------------------------------------------------
__global__ __launch_bounds__(256) void k_xb(
    const float* __restrict__ x, unsigned short* __restrict__ xb16,
    unsigned short* __restrict__ tcat)
{
    const int i = blockIdx.x * 256 + threadIdx.x;   // f32x4 index
    const f32x4 v = ((const f32x4*)x)[i];
    u16x4 o;
    o[0] = f2bf(v[0]); o[1] = f2bf(v[1]); o[2] = f2bf(v[2]); o[3] = f2bf(v[3]);
    *(u16x4*)(xb16 + (size_t)i * 4) = o;
    const int node = i >> 4;
    const int fb = (i & 15) * 4;
    *(u16x4*)(tcat + (size_t)node * 192 + fb) = o;
}

// ---------------------------------------------------------------------------
// Fused pass kernel. Block 0: lmax power-iteration half (25 iters; pass 2
// finalizes Rayleigh -> scal). Blocks 1..8192: y = dgl.*in - agg(in), one
// wave per node, simple 4-deep MLP loop (round-6 structure), bf16 gathers
// (one 128B cacheline per edge). Edge records ride the scalar pipe.
// PASS 1: gathers xb16, diag from fp32 x, writes tcat slice1 + y1b.
// PASS 2: gathers y1b,  diag from y1b,   writes tcat slice2.
// ---------------------------------------------------------------------------
template<int PASS>
__global__ __launch_bounds__(1024) void k_fused(
    const float* __restrict__ x, const unsigned short* __restrict__ gsrc,
    const int2* __restrict__ pk_raw, const int2* __restrict__ pk2,
    const int* __restrict__ ptrg,
    const float* __restrict__ dgr, const float* __restrict__ dgl,
    float* __restrict__ vstate, float* __restrict__ scal,
    unsigned short* __restrict__ tcat, unsigned short* __restrict__ y1b)
{
    __shared__ float vA[NNODE];
    __shared__ float vB[NNODE];
    __shared__ float red[17];
    const int t = threadIdx.x;

    if (blockIdx.x == 0) {
        // ---------------- lambda_max partial power iteration ----------------
        const int it0 = (PASS == 1) ? 0 : 25;
        const int it1 = (PASS == 1) ? 25 : 50;

        const int p0 = ptrg[t], p1 = ptrg[t + 1];
        float w[RMAX];
        int src[RMAX];
#pragma unroll
        for (int i = 0; i < RMAX; ++i) {
            if (p0 + i < p1) {
                const int2 e = pk_raw[p0 + i];
                w[i] = __int_as_float(e.x);
                src[i] = e.y;
            } else {
                w[i] = 0.f;
                src[i] = 0;
            }
        }
        const int tp0 = p0 + RMAX;
        const float dgv = dgr[t];

        vA[t] = (PASS == 1) ? 0.03125f : vstate[t];
        __syncthreads();

        float* cur = vA;
        float* nxt = vB;

        for (int it = it0; it < it1; ++it) {
            float u = dgv * cur[t];
#pragma unroll
            for (int i = 0; i < RMAX; ++i) u -= w[i] * cur[src[i]];
            for (int p = tp0; p < p1; ++p) {
                const int2 e = pk_raw[p];
                u -= __int_as_float(e.x) * cur[e.y];
            }
            if ((it % NORM_EVERY) == NORM_EVERY - 1) {
                float sr = u * u;
#pragma unroll
                for (int o = 32; o > 0; o >>= 1) sr += __shfl_down(sr, o, 64);
                if ((t & 63) == 0) red[t >> 6] = sr;
                __syncthreads();
                if (t < 64) {
                    float xs2 = (t < 16) ? red[t] : 0.f;
#pragma unroll
                    for (int o = 8; o > 0; o >>= 1) xs2 += __shfl_down(xs2, o, 64);
                    if (t == 0) red[16] = 1.0f / (sqrtf(xs2) + 1e-12f);
                }
                __syncthreads();
                nxt[t] = u * red[16];
            } else {
                nxt[t] = u;
            }
            __syncthreads();
            float* tmp = cur; cur = nxt; nxt = tmp;
        }

        if (PASS == 1) {
            vstate[t] = cur[t];
            return;
        }
        float u = dgv * cur[t];
#pragma unroll
        for (int i = 0; i < RMAX; ++i) u -= w[i] * cur[src[i]];
        for (int p = tp0; p < p1; ++p) {
            const int2 e = pk_raw[p];
            u -= __int_as_float(e.x) * cur[e.y];
        }
        float sr = cur[t] * u;
#pragma unroll
        for (int o = 32; o > 0; o >>= 1) sr += __shfl_down(sr, o, 64);
        if ((t & 63) == 0) red[t >> 6] = sr;
        __syncthreads();
        if (t == 0) {
            float lm = 0.f;
            for (int i = 0; i < 16; ++i) lm += red[i];
            scal[0] = lm;
            scal[1] = 2.0f / lm;
        }
        return;
    }

    // ---------------- prop path: one wave per node ----------------
    const int b1   = blockIdx.x - 1;
    const int bid  = ((b1 & 7) << 10) + (b1 >> 3);     // XCD swizzle over 8192
    const int lane = t & 63;
    const int gnode = __builtin_amdgcn_readfirstlane(bid * 16 + (t >> 6));
    const int b = gnode >> 10, d = gnode & 1023;

    const int p0 = __builtin_amdgcn_readfirstlane(ptrg[d]);
    const int p1 = __builtin_amdgcn_readfirstlane(ptrg[d + 1]);
    const char* gb = (const char*)(gsrc + (size_t)b * 65536);
    const unsigned lo = (unsigned)(lane << 1);

    float acc = 0.f;
    int p = p0;
    for (; p + 4 <= p1; p += 4) {        // 4-deep MLP, bf16 gathers
        const int2 e0 = pk2[p],     e1 = pk2[p + 1];
        const int2 e2 = pk2[p + 2], e3 = pk2[p + 3];
        const float v0 = bf2f(*(const unsigned short*)(gb + (unsigned)e0.y + lo));
        const float v1 = bf2f(*(const unsigned short*)(gb + (unsigned)e1.y + lo));
        const float v2 = bf2f(*(const unsigned short*)(gb + (unsigned)e2.y + lo));
        const float v3 = bf2f(*(const unsigned short*)(gb + (unsigned)e3.y + lo));
        acc += __int_as_float(e0.x) * v0;
        acc += __int_as_float(e1.x) * v1;
        acc += __int_as_float(e2.x) * v2;
        acc += __int_as_float(e3.x) * v3;
    }
    for (; p < p1; ++p) {
        const int2 e = pk2[p];
        acc += __int_as_float(e.x) *
               bf2f(*(const unsigned short*)(gb + (unsigned)e.y + lo));
    }

    float xv;
    if (PASS == 1) xv = x[(size_t)gnode * 64 + lane];
    else           xv = bf2f(gsrc[(size_t)gnode * 64 + lane]);
    const float y = dgl[d] * xv - acc;
    tcat[(size_t)gnode * 192 + PASS * 64 + lane] = f2bf(y);
    if (PASS == 1) y1b[(size_t)gnode * 64 + lane] = f2bf(y);
}

// ---------------------------------------------------------------------------
// Weight conversion WITH lambda-scale folding (after lmax):
//   h = x(W0-W1+W2) + y1*s(W1-4W2) + y2*2s^2*W2,  s = 2/lmax.
// ---------------------------------------------------------------------------
__global__ __launch_bounds__(256) void k_cvtw(
    const float* __restrict__ chebW, const float* __restrict__ convW,
    const float* __restrict__ scal,
    unsigned short* __restrict__ wcatT, unsigned short* __restrict__ cvw)
{
    const int i = blockIdx.x * 256 + threadIdx.x;
    const float s = scal[1];
    if (i < 24576) {
        const int n = i / 192, kk = i % 192;
        const int k = kk & 63;
        const float w0 = chebW[k * 128 + n];
        const float w1 = chebW[8192 + k * 128 + n];
        const float w2 = chebW[16384 + k * 128 + n];
        float val;
        if (kk < 64)       val = w0 - w1 + w2;
        else if (kk < 128) val = s * (w1 - 4.f * w2);
        else               val = 2.f * s * s * w2;
        wcatT[i] = f2bf(val);
    }
    const int j = i - 24576;
    if (j >= 0 && j < 8192) cvw[j] = f2bf(convW[j]);
}

// ---------------------------------------------------------------------------
// bf16 MFMA fused cheb-GEMM + conv1d. Output bf16. (unchanged, proven)
// ---------------------------------------------------------------------------
__global__ __launch_bounds__(256) void k_cheb_mfma(
    const unsigned short* __restrict__ tcat,
    const unsigned short* __restrict__ wcatT,
    const unsigned short* __restrict__ cvw,
    const float* __restrict__ chebB, const float* __restrict__ convB,
    unsigned short* __restrict__ cout)
{
    __shared__ __align__(16) char smem[49152];
    __shared__ float cb_s[HID];
    __shared__ float cvb_s[C1];

    const int t    = threadIdx.x;
    const int lane = t & 63;
    const int wid  = t >> 6;
    const int l15  = lane & 15;
    const int l4   = lane >> 4;
    const int rbase = blockIdx.x * 128;
    const int bb = rbase >> 10;
    const int n0 = rbase & 1023;

    if (t < HID) cb_s[t] = chebB[t];
    if (t < C1)  cvb_s[t] = convB[t];

    for (int it = 0; it < 12; ++it) {
        const int gslot = it * 256 + t;
        const int n = gslot / 24, q = gslot % 24;
        const bf16x8 v = *(const bf16x8*)(wcatT + n * 192 + q * 8);
        *(bf16x8*)(smem + n * 384 + ((q ^ (n & 7)) << 4)) = v;
    }
    __syncthreads();

    const int rw = rbase + wid * 32;
    f32x4 acc[2][8];
#pragma unroll
    for (int m = 0; m < 2; ++m)
#pragma unroll
        for (int n = 0; n < 8; ++n) acc[m][n] = (f32x4)(0.f);

    const unsigned short* ta = tcat + (size_t)(rw + l15) * 192 + l4 * 8;
    bf16x8 a0 = *(const bf16x8*)(ta);
    bf16x8 a1 = *(const bf16x8*)(ta + 16 * 192);

#pragma unroll
    for (int ks = 0; ks < 6; ++ks) {
        bf16x8 na0, na1;
        if (ks < 5) {
            na0 = *(const bf16x8*)(ta + (ks + 1) * 32);
            na1 = *(const bf16x8*)(ta + 16 * 192 + (ks + 1) * 32);
        }
        const int kb = ks * 4 + l4;
#pragma unroll
        for (int nb = 0; nb < 8; ++nb) {
            const int n = nb * 16 + l15;
            const bf16x8 bv =
                *(const bf16x8*)(smem + n * 384 + ((kb ^ (n & 7)) << 4));
            acc[0][nb] = __builtin_amdgcn_mfma_f32_16x16x32_bf16(
                a0, bv, acc[0][nb], 0, 0, 0);
            acc[1][nb] = __builtin_amdgcn_mfma_f32_16x16x32_bf16(
                a1, bv, acc[1][nb], 0, 0, 0);
        }
        a0 = na0; a1 = na1;
    }
    __syncthreads();

#pragma unroll
    for (int mf = 0; mf < 2; ++mf)
#pragma unroll
        for (int nb = 0; nb < 8; ++nb) {
            const int c = nb * 16 + l15;
            const int slot = c >> 3;
            const float cb = cb_s[c];
#pragma unroll
            for (int reg = 0; reg < 4; ++reg) {
                const int node = wid * 32 + mf * 16 + l4 * 4 + reg;
                *(unsigned short*)(smem + node * 256 +
                                   ((slot ^ (node & 7)) << 4) + (c & 7) * 2) =
                    f2bf(acc[mf][nb][reg] + cb);
            }
        }
    for (int it = 0; it < 4; ++it) {
        const int gslot = it * 256 + t;
        const int c1i = gslot >> 4, q = gslot & 15;
        const bf16x8 v = *(const bf16x8*)(cvw + c1i * 128 + q * 8);
        *(bf16x8*)(smem + 32768 + c1i * 256 + ((q ^ (c1i & 7)) << 4)) = v;
    }
    __syncthreads();

    f32x4 acc2[8];
#pragma unroll
    for (int n = 0; n < 8; ++n) acc2[n] = (f32x4)(0.f);

#pragma unroll
    for (int ks = 0; ks < 4; ++ks) {
        const int kb = ks * 4 + l4;
        const int c1a = wid * 16 + l15;
        const bf16x8 av = *(const bf16x8*)(smem + 32768 + c1a * 256 +
                                           ((kb ^ (c1a & 7)) << 4));
#pragma unroll
        for (int nb = 0; nb < 8; ++nb) {
            const int node = nb * 16 + l15;
            const bf16x8 bv =
                *(const bf16x8*)(smem + node * 256 + ((kb ^ (node & 7)) << 4));
            acc2[nb] = __builtin_amdgcn_mfma_f32_16x16x32_bf16(
                av, bv, acc2[nb], 0, 0, 0);
        }
    }

#pragma unroll
    for (int nb = 0; nb < 8; ++nb) {
        const int ng = n0 + nb * 16 + l15;
#pragma unroll
        for (int reg = 0; reg < 4; ++reg) {
            const int c1i = wid * 16 + l4 * 4 + reg;
            cout[(size_t)bb * (C1 * NNODE) + (size_t)c1i * NNODE + ng] =
                f2bf(fmaxf(acc2[nb][reg] + cvb_s[c1i], 0.f));
        }
    }
}

// ---------------------------------------------------------------------------
// fc1 partials (K-split over 256-col chunks), bf16 input; reduce; head.
// ---------------------------------------------------------------------------
__global__ __launch_bounds__(256) void k_fc1(
    const unsigned short* __restrict__ cf, const float* __restrict__ W,
    float* __restrict__ part)
{
    __shared__ float Wt[256 * 33];
    const int t = threadIdx.x;
    const int g = blockIdx.x;
    const int k0 = g * 256;

    for (int i = t; i < 8192; i += 256) {
        const int j = i >> 8, k = i & 255;
        Wt[k * 33 + j] = W[(size_t)j * (C1 * NNODE) + k0 + k];
    }
    __syncthreads();

    const int j = t & 31, bg = t >> 5;
    float acc[16];
#pragma unroll
    for (int i = 0; i < 16; ++i) acc[i] = 0.f;

    const unsigned short* cb = cf + (size_t)(bg * 16) * (C1 * NNODE) + k0;
    for (int k4 = 0; k4 < 64; ++k4) {
        const int kb = k4 * 4;
        const float w0 = Wt[(kb + 0) * 33 + j];
        const float w1 = Wt[(kb + 1) * 33 + j];
        const float w2 = Wt[(kb + 2) * 33 + j];
        const float w3 = Wt[(kb + 3) * 33 + j];
#pragma unroll
        for (int i = 0; i < 16; ++i) {
            const u16x4 cv = *(const u16x4*)&cb[(size_t)i * (C1 * NNODE) + kb];
            acc[i] += bf2f(cv[0]) * w0 + bf2f(cv[1]) * w1 +
                      bf2f(cv[2]) * w2 + bf2f(cv[3]) * w3;
        }
    }
#pragma unroll
    for (int i = 0; i < 16; ++i)
        part[(size_t)g * 4096 + (size_t)(bg * 16 + i) * 32 + j] = acc[i];
}

__global__ __launch_bounds__(256) void k_red(
    const float* __restrict__ part, float* __restrict__ z)
{
    const int o = blockIdx.x * 256 + threadIdx.x;
    float s = 0.f;
    for (int g = 0; g < 256; ++g) s += part[(size_t)g * 4096 + o];
    z[o] = s;
}

__global__ __launch_bounds__(128) void k_head(
    const float* __restrict__ z, const float* __restrict__ b1,
    const float* __restrict__ W2, const float* __restrict__ b2,
    float* __restrict__ outp)
{
    const int b = threadIdx.x;
    float a[32];
#pragma unroll
    for (int j = 0; j < 32; ++j) a[j] = z[b * 32 + j] + b1[j];
    float l[4];
#pragma unroll
    for (int c = 0; c < 4; ++c) {
        float s = b2[c];
#pragma unroll
        for (int j = 0; j < 32; ++j) s += W2[c * 32 + j] * a[j];
        l[c] = s;
    }
    const float m = fmaxf(fmaxf(l[0], l[1]), fmaxf(l[2], l[3]));
    const float e0 = expf(l[0] - m), e1 = expf(l[1] - m);
    const float e2 = expf(l[2] - m), e3 = expf(l[3] - m);
    const float inv = 1.f / (e0 + e1 + e2 + e3);
    outp[b * 4 + 0] = e0 * inv;
    outp[b * 4 + 1] = e1 * inv;
    outp[b * 4 + 2] = e2 * inv;
    outp[b * 4 + 3] = e3 * inv;
}

// ---------------------------------------------------------------------------
extern "C" void kernel_launch(void* const* d_in, const int* in_sizes, int n_in,
                              void* d_out, int out_size, void* d_ws, size_t ws_size,
                              hipStream_t stream)
{
    const float* x     = (const float*)d_in[0];
    const int*   ei    = (const int*)d_in[1];
    const float* ew    = (const float*)d_in[2];
    const float* chebW = (const float*)d_in[3];
    const float* chebB = (const float*)d_in[4];
    const float* convW = (const float*)d_in[5];
    const float* convB = (const float*)d_in[6];
    const float* fc1W  = (const float*)d_in[7];
    const float* fc1B  = (const float*)d_in[8];
    const float* fc2W  = (const float*)d_in[9];
    const float* fc2B  = (const float*)d_in[10];
    float* out = (float*)d_out;

    char* ws = (char*)d_ws;
    float* scal   = (float*)(ws + 0);
    float* vstate = (float*)(ws + 4096);
    char*  partb  = ws + 8192;                      // 4MB multi-use region
    int*   ptr  = (int*)(partb + 8192);
    float* dgr  = (float*)(partb + 16384);
    float* dgl  = (float*)(partb + 20480);
    int2*  pk   = (int2*)(partb + 24576);           // 128KB (raw w, src)
    unsigned short* wcatT = (unsigned short*)(partb + 262144);  // 48KB
    unsigned short* cvwB  = (unsigned short*)(partb + 327680);  // 16KB
    int2*  pk2  = (int2*)(partb + 458752);          // 128KB (relu w, src*128)
    float* part = (float*)partb;                    // fc1 partials (after cheb)
    float* z    = (float*)(ws + 4202496);           // 64KB
    unsigned short* xb16 = (unsigned short*)(ws + 4268032);   // 16MB
    unsigned short* y1b  = (unsigned short*)(ws + 21045248);  // 16MB
    unsigned short* tcat = (unsigned short*)(ws + 37822464);  // 48MB
    unsigned short* cbuf = (unsigned short*)(ws + 88154112);  // 16MB

    k_csr<<<dim3(1),    dim3(1024), 0, stream>>>(ei, ew, ptr, dgr, dgl, pk, pk2);
    k_xb <<<dim3(8192), dim3(256),  0, stream>>>(x, xb16, tcat);

    k_fused<1><<<dim3(8193), dim3(1024), 0, stream>>>(
        x, xb16, pk, pk2, ptr, dgr, dgl, vstate, scal, tcat, y1b);
    k_fused<2><<<dim3(8193), dim3(1024), 0, stream>>>(
        x, y1b, pk, pk2, ptr, dgr, dgl, vstate, scal, tcat, y1b);

    k_cvtw<<<dim3(128), dim3(256), 0, stream>>>(chebW, convW, scal, wcatT, cvwB);

    k_cheb_mfma<<<dim3(BN / 128), dim3(256), 0, stream>>>(
        tcat, wcatT, cvwB, chebB, convB, cbuf);

    k_fc1<<<dim3(256), dim3(256), 0, stream>>>(cbuf, fc1W, part);
    k_red<<<dim3(16), dim3(256), 0, stream>>>(part, z);
    k_head<<<dim3(1), dim3(128), 0, stream>>>(z, fc1B, fc2W, fc2B, out);
}

// Round 13
// 276.409 us; speedup vs baseline: 1.8833x; 1.0908x over previous
//
#include <hip/hip_runtime.h>
#include <math.h>

#define BATCH 128
#define NNODE 1024
#define EG 16384
#define F_IN 64
#define HID 128
#define C1 64
#define C2 32
#define NCLS 4
#define POWER_ITERS 50
#define BN (BATCH * NNODE)
#define RMAX 28
#define NORM_EVERY 5
#define FSLOT 32

typedef float f32x4 __attribute__((ext_vector_type(4)));
typedef __bf16 bf16x8 __attribute__((ext_vector_type(8)));
typedef unsigned short u16x4 __attribute__((ext_vector_type(4)));

__device__ inline unsigned short f2bf(float f) {   // round-to-nearest-even
    unsigned int u = __float_as_uint(f);
    u += 0x7fffu + ((u >> 16) & 1u);
    return (unsigned short)(u >> 16);
}
__device__ inline float bf2f(unsigned short h) {
    return __uint_as_float((unsigned int)h << 16);
}

// ---------------------------------------------------------------------------
// CSR build (by dst), single block. pk {raw_w, src} for lmax;
// pk2 {relu_w, src*128} CSR for deg>FSLOT tail; pkF fixed [node][32] table
// (zero-weight padding) for the latency-optimized prop gather.
// ---------------------------------------------------------------------------
__global__ __launch_bounds__(1024) void k_csr(
    const int* __restrict__ ei, const float* __restrict__ ew,
    int* __restrict__ ptr_g, float* __restrict__ dgr_g,
    float* __restrict__ dgl_g, int2* __restrict__ packed,
    int2* __restrict__ packed2, int2* __restrict__ pkF)
{
    __shared__ int   cnt[NNODE];
    __shared__ float dgr[NNODE];
    __shared__ float dgl[NNODE];
    __shared__ int   s[NNODE];
    __shared__ int   base[NNODE];
    const int t = threadIdx.x;

    cnt[t] = 0; dgr[t] = 0.f; dgl[t] = 0.f;
#pragma unroll
    for (int i = 0; i < FSLOT; ++i)          // zero the fixed table
        pkF[t * FSLOT + i] = make_int2(0, 0);

    int es[16], ed[16];
    float w[16];
#pragma unroll
    for (int i = 0; i < 16; ++i) {
        const int e = i * 1024 + t;
        es[i] = ei[e];
        ed[i] = ei[EG + e];
        w[i]  = ew[e];
    }
    __syncthreads();
#pragma unroll
    for (int i = 0; i < 16; ++i) {
        atomicAdd(&cnt[ed[i]], 1);
        atomicAdd(&dgr[es[i]], w[i]);
        atomicAdd(&dgl[es[i]], fmaxf(w[i], 0.f));
    }
    __syncthreads();
    dgr_g[t] = dgr[t];
    dgl_g[t] = dgl[t];

    const int v = cnt[t];
    s[t] = v;
    __syncthreads();
    for (int o = 1; o < 1024; o <<= 1) {
        const int a = (t >= o) ? s[t - o] : 0;
        __syncthreads();
        s[t] += a;
        __syncthreads();
    }
    const int excl = s[t] - v;
    ptr_g[t] = excl;
    base[t]  = excl;
    if (t == 1023) ptr_g[1024] = s[1023];
    __syncthreads();

#pragma unroll
    for (int i = 0; i < 16; ++i) {
        const int d = ed[i];
        const int p = atomicAdd(&base[d], 1);
        const float rw = fmaxf(w[i], 0.f);
        packed[p]  = make_int2(__float_as_int(w[i]), es[i]);
        packed2[p] = make_int2(__float_as_int(rw), es[i] << 7);
        const int local = p - (s[d] - cnt[d]);
        if (local < FSLOT)
            pkF[d * FSLOT + local] = make_int2(__float_as_int(rw), es[i] << 7);
    }
}

// ---------------------------------------------------------------------------
// x -> xb16 [BN][64] bf16 (gather source) + tcat slice 0.
// ---------------------------------------------------------------------------
__global__ __launch_bounds__(256) void k_xb(
    const float* __restrict__ x, unsigned short* __restrict__ xb16,
    unsigned short* __restrict__ tcat)
{
    const int i = blockIdx.x * 256 + threadIdx.x;   // f32x4 index
    const f32x4 v = ((const f32x4*)x)[i];
    u16x4 o;
    o[0] = f2bf(v[0]); o[1] = f2bf(v[1]); o[2] = f2bf(v[2]); o[3] = f2bf(v[3]);
    *(u16x4*)(xb16 + (size_t)i * 4) = o;
    const int node = i >> 4;
    const int fb = (i & 15) * 4;
    *(u16x4*)(tcat + (size_t)node * 192 + fb) = o;
}

// ---------------------------------------------------------------------------
// Fused pass kernel. Block 0: lmax half (25 iters; pass 2 adds Rayleigh).
// Blocks 1..8192: y = dgl.*in - agg(in), one wave per node. Edge records
// from the FIXED table pkF[d][32]: 16 scalar-loaded records -> 16 gathers
// issued back-to-back (16-deep MLP, no clamps); second 16-round only if
// deg>16 (wave-uniform); deg>32 tail via ptr/pk2 CSR.
// ---------------------------------------------------------------------------
template<int PASS>
__global__ __launch_bounds__(1024) void k_fused(
    const float* __restrict__ x, const unsigned short* __restrict__ gsrc,
    const int2* __restrict__ pk_raw, const int2* __restrict__ pk2,
    const int2* __restrict__ pkF, const int* __restrict__ ptrg,
    const float* __restrict__ dgr, const float* __restrict__ dgl,
    float* __restrict__ vstate, float* __restrict__ scal,
    unsigned short* __restrict__ tcat, unsigned short* __restrict__ y1b)
{
    __shared__ float vA[NNODE];
    __shared__ float vB[NNODE];
    __shared__ float red[17];
    const int t = threadIdx.x;

    if (blockIdx.x == 0) {
        // ---------------- lambda_max partial power iteration ----------------
        const int it0 = (PASS == 1) ? 0 : 25;
        const int it1 = (PASS == 1) ? 25 : 50;

        const int p0 = ptrg[t], p1 = ptrg[t + 1];
        float w[RMAX];
        int src[RMAX];
#pragma unroll
        for (int i = 0; i < RMAX; ++i) {
            if (p0 + i < p1) {
                const int2 e = pk_raw[p0 + i];
                w[i] = __int_as_float(e.x);
                src[i] = e.y;
            } else {
                w[i] = 0.f;
                src[i] = 0;
            }
        }
        const int tp0 = p0 + RMAX;
        const float dgv = dgr[t];

        vA[t] = (PASS == 1) ? 0.03125f : vstate[t];
        __syncthreads();

        float* cur = vA;
        float* nxt = vB;

        for (int it = it0; it < it1; ++it) {
            float u = dgv * cur[t];
#pragma unroll
            for (int i = 0; i < RMAX; ++i) u -= w[i] * cur[src[i]];
            for (int p = tp0; p < p1; ++p) {
                const int2 e = pk_raw[p];
                u -= __int_as_float(e.x) * cur[e.y];
            }
            if ((it % NORM_EVERY) == NORM_EVERY - 1) {
                float sr = u * u;
#pragma unroll
                for (int o = 32; o > 0; o >>= 1) sr += __shfl_down(sr, o, 64);
                if ((t & 63) == 0) red[t >> 6] = sr;
                __syncthreads();
                if (t < 64) {
                    float xs2 = (t < 16) ? red[t] : 0.f;
#pragma unroll
                    for (int o = 8; o > 0; o >>= 1) xs2 += __shfl_down(xs2, o, 64);
                    if (t == 0) red[16] = 1.0f / (sqrtf(xs2) + 1e-12f);
                }
                __syncthreads();
                nxt[t] = u * red[16];
            } else {
                nxt[t] = u;
            }
            __syncthreads();
            float* tmp = cur; cur = nxt; nxt = tmp;
        }

        if (PASS == 1) {
            vstate[t] = cur[t];
            return;
        }
        float u = dgv * cur[t];
#pragma unroll
        for (int i = 0; i < RMAX; ++i) u -= w[i] * cur[src[i]];
        for (int p = tp0; p < p1; ++p) {
            const int2 e = pk_raw[p];
            u -= __int_as_float(e.x) * cur[e.y];
        }
        float sr = cur[t] * u;
#pragma unroll
        for (int o = 32; o > 0; o >>= 1) sr += __shfl_down(sr, o, 64);
        if ((t & 63) == 0) red[t >> 6] = sr;
        __syncthreads();
        if (t == 0) {
            float lm = 0.f;
            for (int i = 0; i < 16; ++i) lm += red[i];
            scal[0] = lm;
            scal[1] = 2.0f / lm;
        }
        return;
    }

    // ---------------- prop path: one wave per node ----------------
    const int b1   = blockIdx.x - 1;
    const int bid  = ((b1 & 7) << 10) + (b1 >> 3);     // XCD swizzle over 8192
    const int lane = t & 63;
    const int gnode = __builtin_amdgcn_readfirstlane(bid * 16 + (t >> 6));
    const int b = gnode >> 10, d = gnode & 1023;

    const int p0 = __builtin_amdgcn_readfirstlane(ptrg[d]);
    const int p1 = __builtin_amdgcn_readfirstlane(ptrg[d + 1]);
    const int deg = p1 - p0;
    const char* gb = (const char*)(gsrc + (size_t)b * 65536);
    const unsigned lo = (unsigned)(lane << 1);
    const int2* pf = pkF + d * FSLOT;

    float acc0 = 0.f, acc1 = 0.f, acc2 = 0.f, acc3 = 0.f;

    {   // round 1: slots 0..15, all gathers independent
        int2 er[16];
#pragma unroll
        for (int i = 0; i < 16; ++i) er[i] = pf[i];
        float vv[16];
#pragma unroll
        for (int i = 0; i < 16; ++i)
            vv[i] = bf2f(*(const unsigned short*)(gb + (unsigned)er[i].y + lo));
#pragma unroll
        for (int i = 0; i < 16; i += 4) {
            acc0 += __int_as_float(er[i + 0].x) * vv[i + 0];
            acc1 += __int_as_float(er[i + 1].x) * vv[i + 1];
            acc2 += __int_as_float(er[i + 2].x) * vv[i + 2];
            acc3 += __int_as_float(er[i + 3].x) * vv[i + 3];
        }
    }
    if (deg > 16) {   // round 2: slots 16..31 (wave-uniform branch)
        int2 er[16];
#pragma unroll
        for (int i = 0; i < 16; ++i) er[i] = pf[16 + i];
        float vv[16];
#pragma unroll
        for (int i = 0; i < 16; ++i)
            vv[i] = bf2f(*(const unsigned short*)(gb + (unsigned)er[i].y + lo));
#pragma unroll
        for (int i = 0; i < 16; i += 4) {
            acc0 += __int_as_float(er[i + 0].x) * vv[i + 0];
            acc1 += __int_as_float(er[i + 1].x) * vv[i + 1];
            acc2 += __int_as_float(er[i + 2].x) * vv[i + 2];
            acc3 += __int_as_float(er[i + 3].x) * vv[i + 3];
        }
    }
    for (int p = p0 + FSLOT; p < p1; ++p) {   // rare tail (deg > 32)
        const int2 e = pk2[p];
        acc0 += __int_as_float(e.x) *
                bf2f(*(const unsigned short*)(gb + (unsigned)e.y + lo));
    }
    const float acc = (acc0 + acc1) + (acc2 + acc3);

    float xv;
    if (PASS == 1) xv = x[(size_t)gnode * 64 + lane];
    else           xv = bf2f(gsrc[(size_t)gnode * 64 + lane]);
    const float y = dgl[d] * xv - acc;
    tcat[(size_t)gnode * 192 + PASS * 64 + lane] = f2bf(y);
    if (PASS == 1) y1b[(size_t)gnode * 64 + lane] = f2bf(y);
}

// ---------------------------------------------------------------------------
// Weight conversion WITH lambda-scale folding (after lmax):
//   h = x(W0-W1+W2) + y1*s(W1-4W2) + y2*2s^2*W2,  s = 2/lmax.
// ---------------------------------------------------------------------------
__global__ __launch_bounds__(256) void k_cvtw(
    const float* __restrict__ chebW, const float* __restrict__ convW,
    const float* __restrict__ scal,
    unsigned short* __restrict__ wcatT, unsigned short* __restrict__ cvw)
{
    const int i = blockIdx.x * 256 + threadIdx.x;
    const float s = scal[1];
    if (i < 24576) {
        const int n = i / 192, kk = i % 192;
        const int k = kk & 63;
        const float w0 = chebW[k * 128 + n];
        const float w1 = chebW[8192 + k * 128 + n];
        const float w2 = chebW[16384 + k * 128 + n];
        float val;
        if (kk < 64)       val = w0 - w1 + w2;
        else if (kk < 128) val = s * (w1 - 4.f * w2);
        else               val = 2.f * s * s * w2;
        wcatT[i] = f2bf(val);
    }
    const int j = i - 24576;
    if (j >= 0 && j < 8192) cvw[j] = f2bf(convW[j]);
}

// ---------------------------------------------------------------------------
// bf16 MFMA fused cheb-GEMM + conv1d. Output bf16. (unchanged, proven)
// ---------------------------------------------------------------------------
__global__ __launch_bounds__(256) void k_cheb_mfma(
    const unsigned short* __restrict__ tcat,
    const unsigned short* __restrict__ wcatT,
    const unsigned short* __restrict__ cvw,
    const float* __restrict__ chebB, const float* __restrict__ convB,
    unsigned short* __restrict__ cout)
{
    __shared__ __align__(16) char smem[49152];
    __shared__ float cb_s[HID];
    __shared__ float cvb_s[C1];

    const int t    = threadIdx.x;
    const int lane = t & 63;
    const int wid  = t >> 6;
    const int l15  = lane & 15;
    const int l4   = lane >> 4;
    const int rbase = blockIdx.x * 128;
    const int bb = rbase >> 10;
    const int n0 = rbase & 1023;

    if (t < HID) cb_s[t] = chebB[t];
    if (t < C1)  cvb_s[t] = convB[t];

    for (int it = 0; it < 12; ++it) {
        const int gslot = it * 256 + t;
        const int n = gslot / 24, q = gslot % 24;
        const bf16x8 v = *(const bf16x8*)(wcatT + n * 192 + q * 8);
        *(bf16x8*)(smem + n * 384 + ((q ^ (n & 7)) << 4)) = v;
    }
    __syncthreads();

    const int rw = rbase + wid * 32;
    f32x4 acc[2][8];
#pragma unroll
    for (int m = 0; m < 2; ++m)
#pragma unroll
        for (int n = 0; n < 8; ++n) acc[m][n] = (f32x4)(0.f);

    const unsigned short* ta = tcat + (size_t)(rw + l15) * 192 + l4 * 8;
    bf16x8 a0 = *(const bf16x8*)(ta);
    bf16x8 a1 = *(const bf16x8*)(ta + 16 * 192);

#pragma unroll
    for (int ks = 0; ks < 6; ++ks) {
        bf16x8 na0, na1;
        if (ks < 5) {
            na0 = *(const bf16x8*)(ta + (ks + 1) * 32);
            na1 = *(const bf16x8*)(ta + 16 * 192 + (ks + 1) * 32);
        }
        const int kb = ks * 4 + l4;
#pragma unroll
        for (int nb = 0; nb < 8; ++nb) {
            const int n = nb * 16 + l15;
            const bf16x8 bv =
                *(const bf16x8*)(smem + n * 384 + ((kb ^ (n & 7)) << 4));
            acc[0][nb] = __builtin_amdgcn_mfma_f32_16x16x32_bf16(
                a0, bv, acc[0][nb], 0, 0, 0);
            acc[1][nb] = __builtin_amdgcn_mfma_f32_16x16x32_bf16(
                a1, bv, acc[1][nb], 0, 0, 0);
        }
        a0 = na0; a1 = na1;
    }
    __syncthreads();

#pragma unroll
    for (int mf = 0; mf < 2; ++mf)
#pragma unroll
        for (int nb = 0; nb < 8; ++nb) {
            const int c = nb * 16 + l15;
            const int slot = c >> 3;
            const float cb = cb_s[c];
#pragma unroll
            for (int reg = 0; reg < 4; ++reg) {
                const int node = wid * 32 + mf * 16 + l4 * 4 + reg;
                *(unsigned short*)(smem + node * 256 +
                                   ((slot ^ (node & 7)) << 4) + (c & 7) * 2) =
                    f2bf(acc[mf][nb][reg] + cb);
            }
        }
    for (int it = 0; it < 4; ++it) {
        const int gslot = it * 256 + t;
        const int c1i = gslot >> 4, q = gslot & 15;
        const bf16x8 v = *(const bf16x8*)(cvw + c1i * 128 + q * 8);
        *(bf16x8*)(smem + 32768 + c1i * 256 + ((q ^ (c1i & 7)) << 4)) = v;
    }
    __syncthreads();

    f32x4 acc2[8];
#pragma unroll
    for (int n = 0; n < 8; ++n) acc2[n] = (f32x4)(0.f);

#pragma unroll
    for (int ks = 0; ks < 4; ++ks) {
        const int kb = ks * 4 + l4;
        const int c1a = wid * 16 + l15;
        const bf16x8 av = *(const bf16x8*)(smem + 32768 + c1a * 256 +
                                           ((kb ^ (c1a & 7)) << 4));
#pragma unroll
        for (int nb = 0; nb < 8; ++nb) {
            const int node = nb * 16 + l15;
            const bf16x8 bv =
                *(const bf16x8*)(smem + node * 256 + ((kb ^ (node & 7)) << 4));
            acc2[nb] = __builtin_amdgcn_mfma_f32_16x16x32_bf16(
                av, bv, acc2[nb], 0, 0, 0);
        }
    }

#pragma unroll
    for (int nb = 0; nb < 8; ++nb) {
        const int ng = n0 + nb * 16 + l15;
#pragma unroll
        for (int reg = 0; reg < 4; ++reg) {
            const int c1i = wid * 16 + l4 * 4 + reg;
            cout[(size_t)bb * (C1 * NNODE) + (size_t)c1i * NNODE + ng] =
                f2bf(fmaxf(acc2[nb][reg] + cvb_s[c1i], 0.f));
        }
    }
}

// ---------------------------------------------------------------------------
// fc1 partials (K-split over 256-col chunks), bf16 input; reduce; head.
// ---------------------------------------------------------------------------
__global__ __launch_bounds__(256) void k_fc1(
    const unsigned short* __restrict__ cf, const float* __restrict__ W,
    float* __restrict__ part)
{
    __shared__ float Wt[256 * 33];
    const int t = threadIdx.x;
    const int g = blockIdx.x;
    const int k0 = g * 256;

    for (int i = t; i < 8192; i += 256) {
        const int j = i >> 8, k = i & 255;
        Wt[k * 33 + j] = W[(size_t)j * (C1 * NNODE) + k0 + k];
    }
    __syncthreads();

    const int j = t & 31, bg = t >> 5;
    float acc[16];
#pragma unroll
    for (int i = 0; i < 16; ++i) acc[i] = 0.f;

    const unsigned short* cb = cf + (size_t)(bg * 16) * (C1 * NNODE) + k0;
    for (int k4 = 0; k4 < 64; ++k4) {
        const int kb = k4 * 4;
        const float w0 = Wt[(kb + 0) * 33 + j];
        const float w1 = Wt[(kb + 1) * 33 + j];
        const float w2 = Wt[(kb + 2) * 33 + j];
        const float w3 = Wt[(kb + 3) * 33 + j];
#pragma unroll
        for (int i = 0; i < 16; ++i) {
            const u16x4 cv = *(const u16x4*)&cb[(size_t)i * (C1 * NNODE) + kb];
            acc[i] += bf2f(cv[0]) * w0 + bf2f(cv[1]) * w1 +
                      bf2f(cv[2]) * w2 + bf2f(cv[3]) * w3;
        }
    }
#pragma unroll
    for (int i = 0; i < 16; ++i)
        part[(size_t)g * 4096 + (size_t)(bg * 16 + i) * 32 + j] = acc[i];
}

__global__ __launch_bounds__(256) void k_red(
    const float* __restrict__ part, float* __restrict__ z)
{
    const int o = blockIdx.x * 256 + threadIdx.x;
    float s = 0.f;
    for (int g = 0; g < 256; ++g) s += part[(size_t)g * 4096 + o];
    z[o] = s;
}

__global__ __launch_bounds__(128) void k_head(
    const float* __restrict__ z, const float* __restrict__ b1,
    const float* __restrict__ W2, const float* __restrict__ b2,
    float* __restrict__ outp)
{
    const int b = threadIdx.x;
    float a[32];
#pragma unroll
    for (int j = 0; j < 32; ++j) a[j] = z[b * 32 + j] + b1[j];
    float l[4];
#pragma unroll
    for (int c = 0; c < 4; ++c) {
        float s = b2[c];
#pragma unroll
        for (int j = 0; j < 32; ++j) s += W2[c * 32 + j] * a[j];
        l[c] = s;
    }
    const float m = fmaxf(fmaxf(l[0], l[1]), fmaxf(l[2], l[3]));
    const float e0 = expf(l[0] - m), e1 = expf(l[1] - m);
    const float e2 = expf(l[2] - m), e3 = expf(l[3] - m);
    const float inv = 1.f / (e0 + e1 + e2 + e3);
    outp[b * 4 + 0] = e0 * inv;
    outp[b * 4 + 1] = e1 * inv;
    outp[b * 4 + 2] = e2 * inv;
    outp[b * 4 + 3] = e3 * inv;
}

// ---------------------------------------------------------------------------
extern "C" void kernel_launch(void* const* d_in, const int* in_sizes, int n_in,
                              void* d_out, int out_size, void* d_ws, size_t ws_size,
                              hipStream_t stream)
{
    const float* x     = (const float*)d_in[0];
    const int*   ei    = (const int*)d_in[1];
    const float* ew    = (const float*)d_in[2];
    const float* chebW = (const float*)d_in[3];
    const float* chebB = (const float*)d_in[4];
    const float* convW = (const float*)d_in[5];
    const float* convB = (const float*)d_in[6];
    const float* fc1W  = (const float*)d_in[7];
    const float* fc1B  = (const float*)d_in[8];
    const float* fc2W  = (const float*)d_in[9];
    const float* fc2B  = (const float*)d_in[10];
    float* out = (float*)d_out;

    char* ws = (char*)d_ws;
    float* scal   = (float*)(ws + 0);
    float* vstate = (float*)(ws + 4096);
    char*  partb  = ws + 8192;                      // 4MB multi-use region
    int*   ptr  = (int*)(partb + 8192);
    float* dgr  = (float*)(partb + 16384);
    float* dgl  = (float*)(partb + 20480);
    int2*  pk   = (int2*)(partb + 24576);           // 128KB (raw w, src)
    unsigned short* wcatT = (unsigned short*)(partb + 262144);  // 48KB
    unsigned short* cvwB  = (unsigned short*)(partb + 327680);  // 16KB
    int2*  pk2  = (int2*)(partb + 458752);          // 128KB (relu w, src*128)
    int2*  pkF  = (int2*)(partb + 589824);          // 256KB fixed [1024][32]
    float* part = (float*)partb;                    // fc1 partials (after cheb)
    float* z    = (float*)(ws + 4202496);           // 64KB
    unsigned short* xb16 = (unsigned short*)(ws + 4268032);   // 16MB
    unsigned short* y1b  = (unsigned short*)(ws + 21045248);  // 16MB
    unsigned short* tcat = (unsigned short*)(ws + 37822464);  // 48MB
    unsigned short* cbuf = (unsigned short*)(ws + 88154112);  // 16MB

    k_csr<<<dim3(1),    dim3(1024), 0, stream>>>(ei, ew, ptr, dgr, dgl, pk,
                                                 pk2, pkF);
    k_xb <<<dim3(8192), dim3(256),  0, stream>>>(x, xb16, tcat);

    k_fused<1><<<dim3(8193), dim3(1024), 0, stream>>>(
        x, xb16, pk, pk2, pkF, ptr, dgr, dgl, vstate, scal, tcat, y1b);
    k_fused<2><<<dim3(8193), dim3(1024), 0, stream>>>(
        x, y1b, pk, pk2, pkF, ptr, dgr, dgl, vstate, scal, tcat, y1b);

    k_cvtw<<<dim3(128), dim3(256), 0, stream>>>(chebW, convW, scal, wcatT, cvwB);

    k_cheb_mfma<<<dim3(BN / 128), dim3(256), 0, stream>>>(
        tcat, wcatT, cvwB, chebB, convB, cbuf);

    k_fc1<<<dim3(256), dim3(256), 0, stream>>>(cbuf, fc1W, part);
    k_red<<<dim3(16), dim3(256), 0, stream>>>(part, z);
    k_head<<<dim3(1), dim3(128), 0, stream>>>(z, fc1B, fc2W, fc2B, out);
}

// Round 14
// 274.969 us; speedup vs baseline: 1.8932x; 1.0052x over previous
//
#include <hip/hip_runtime.h>
#include <math.h>

#define BATCH 128
#define NNODE 1024
#define EG 16384
#define F_IN 64
#define HID 128
#define C1 64
#define C2 32
#define NCLS 4
#define POWER_ITERS 50
#define BN (BATCH * NNODE)
#define RMAX 28
#define NORM_EVERY 5
#define FSLOT 32

typedef float f32x4 __attribute__((ext_vector_type(4)));
typedef __bf16 bf16x8 __attribute__((ext_vector_type(8)));
typedef unsigned short u16x4 __attribute__((ext_vector_type(4)));

__device__ inline unsigned short f2bf(float f) {   // round-to-nearest-even
    unsigned int u = __float_as_uint(f);
    u += 0x7fffu + ((u >> 16) & 1u);
    return (unsigned short)(u >> 16);
}
__device__ inline float bf2f(unsigned short h) {
    return __uint_as_float((unsigned int)h << 16);
}

// ---------------------------------------------------------------------------
// Multi-block CSR build (round-2 shape: the single-block builder was 86us
// with 0.16% occupancy). zero -> count -> scan -> fill.
// ---------------------------------------------------------------------------
__global__ __launch_bounds__(256) void k_zero(
    int* __restrict__ cnt, float* __restrict__ dgr, float* __restrict__ dgl,
    int2* __restrict__ pkF)
{
    const int i = blockIdx.x * 256 + threadIdx.x;   // 0..65535
    if (i < NNODE) { cnt[i] = 0; dgr[i] = 0.f; dgl[i] = 0.f; }
    if (i < NNODE * FSLOT) pkF[i] = make_int2(0, 0);
}

__global__ __launch_bounds__(256) void k_count(
    const int* __restrict__ ei, const float* __restrict__ ew,
    int* __restrict__ cnt, float* __restrict__ dgr, float* __restrict__ dgl)
{
    const int e = blockIdx.x * 256 + threadIdx.x;
    const int s = ei[e], d = ei[EG + e];
    const float w = ew[e];
    atomicAdd(&cnt[d], 1);
    atomicAdd(&dgr[s], w);
    atomicAdd(&dgl[s], fmaxf(w, 0.f));
}

__global__ __launch_bounds__(1024) void k_scan(
    const int* __restrict__ cnt, int* __restrict__ ptr, int* __restrict__ pos)
{
    __shared__ int s[NNODE];
    const int t = threadIdx.x;
    const int v = cnt[t];
    s[t] = v;
    __syncthreads();
    for (int o = 1; o < 1024; o <<= 1) {
        const int a = (t >= o) ? s[t - o] : 0;
        __syncthreads();
        s[t] += a;
        __syncthreads();
    }
    const int excl = s[t] - v;
    ptr[t] = excl;
    pos[t] = excl;
    if (t == 1023) ptr[1024] = s[1023];
}

__global__ __launch_bounds__(256) void k_fill(
    const int* __restrict__ ei, const float* __restrict__ ew,
    const int* __restrict__ ptr, int* __restrict__ pos,
    int2* __restrict__ packed, int2* __restrict__ packed2,
    int2* __restrict__ pkF)
{
    const int e = blockIdx.x * 256 + threadIdx.x;
    const int s = ei[e], d = ei[EG + e];
    const float w = ew[e];
    const float rw = fmaxf(w, 0.f);
    const int p = atomicAdd(&pos[d], 1);
    packed[p]  = make_int2(__float_as_int(w), s);
    packed2[p] = make_int2(__float_as_int(rw), s << 7);
    const int local = p - ptr[d];
    if (local < FSLOT)
        pkF[d * FSLOT + local] = make_int2(__float_as_int(rw), s << 7);
}

// ---------------------------------------------------------------------------
// x -> xb16 [BN][64] bf16 (gather source) + tcat slice 0.
// ---------------------------------------------------------------------------
__global__ __launch_bounds__(256) void k_xb(
    const float* __restrict__ x, unsigned short* __restrict__ xb16,
    unsigned short* __restrict__ tcat)
{
    const int i = blockIdx.x * 256 + threadIdx.x;   // f32x4 index
    const f32x4 v = ((const f32x4*)x)[i];
    u16x4 o;
    o[0] = f2bf(v[0]); o[1] = f2bf(v[1]); o[2] = f2bf(v[2]); o[3] = f2bf(v[3]);
    *(u16x4*)(xb16 + (size_t)i * 4) = o;
    const int node = i >> 4;
    const int fb = (i & 15) * 4;
    *(u16x4*)(tcat + (size_t)node * 192 + fb) = o;
}

// ---------------------------------------------------------------------------
// Fused pass kernel. Block 0: lmax half (25 iters; pass 2 adds Rayleigh).
// Blocks 1..8192: y = dgl.*in - agg(in), one wave per node. Edge records
// from the FIXED table pkF[d][32]: 16 scalar-loaded records -> 16 gathers
// issued back-to-back; second 16-round only if deg>16 (wave-uniform);
// deg>32 tail via ptr/pk2 CSR.
// ---------------------------------------------------------------------------
template<int PASS>
__global__ __launch_bounds__(1024) void k_fused(
    const float* __restrict__ x, const unsigned short* __restrict__ gsrc,
    const int2* __restrict__ pk_raw, const int2* __restrict__ pk2,
    const int2* __restrict__ pkF, const int* __restrict__ ptrg,
    const float* __restrict__ dgr, const float* __restrict__ dgl,
    float* __restrict__ vstate, float* __restrict__ scal,
    unsigned short* __restrict__ tcat, unsigned short* __restrict__ y1b)
{
    __shared__ float vA[NNODE];
    __shared__ float vB[NNODE];
    __shared__ float red[17];
    const int t = threadIdx.x;

    if (blockIdx.x == 0) {
        // ---------------- lambda_max partial power iteration ----------------
        const int it0 = (PASS == 1) ? 0 : 25;
        const int it1 = (PASS == 1) ? 25 : 50;

        const int p0 = ptrg[t], p1 = ptrg[t + 1];
        float w[RMAX];
        int src[RMAX];
#pragma unroll
        for (int i = 0; i < RMAX; ++i) {
            if (p0 + i < p1) {
                const int2 e = pk_raw[p0 + i];
                w[i] = __int_as_float(e.x);
                src[i] = e.y;
            } else {
                w[i] = 0.f;
                src[i] = 0;
            }
        }
        const int tp0 = p0 + RMAX;
        const float dgv = dgr[t];

        vA[t] = (PASS == 1) ? 0.03125f : vstate[t];
        __syncthreads();

        float* cur = vA;
        float* nxt = vB;

        for (int it = it0; it < it1; ++it) {
            float u = dgv * cur[t];
#pragma unroll
            for (int i = 0; i < RMAX; ++i) u -= w[i] * cur[src[i]];
            for (int p = tp0; p < p1; ++p) {
                const int2 e = pk_raw[p];
                u -= __int_as_float(e.x) * cur[e.y];
            }
            if ((it % NORM_EVERY) == NORM_EVERY - 1) {
                float sr = u * u;
#pragma unroll
                for (int o = 32; o > 0; o >>= 1) sr += __shfl_down(sr, o, 64);
                if ((t & 63) == 0) red[t >> 6] = sr;
                __syncthreads();
                if (t < 64) {
                    float xs2 = (t < 16) ? red[t] : 0.f;
#pragma unroll
                    for (int o = 8; o > 0; o >>= 1) xs2 += __shfl_down(xs2, o, 64);
                    if (t == 0) red[16] = 1.0f / (sqrtf(xs2) + 1e-12f);
                }
                __syncthreads();
                nxt[t] = u * red[16];
            } else {
                nxt[t] = u;
            }
            __syncthreads();
            float* tmp = cur; cur = nxt; nxt = tmp;
        }

        if (PASS == 1) {
            vstate[t] = cur[t];
            return;
        }
        float u = dgv * cur[t];
#pragma unroll
        for (int i = 0; i < RMAX; ++i) u -= w[i] * cur[src[i]];
        for (int p = tp0; p < p1; ++p) {
            const int2 e = pk_raw[p];
            u -= __int_as_float(e.x) * cur[e.y];
        }
        float sr = cur[t] * u;
#pragma unroll
        for (int o = 32; o > 0; o >>= 1) sr += __shfl_down(sr, o, 64);
        if ((t & 63) == 0) red[t >> 6] = sr;
        __syncthreads();
        if (t == 0) {
            float lm = 0.f;
            for (int i = 0; i < 16; ++i) lm += red[i];
            scal[0] = lm;
            scal[1] = 2.0f / lm;
        }
        return;
    }

    // ---------------- prop path: one wave per node ----------------
    const int b1   = blockIdx.x - 1;
    const int bid  = ((b1 & 7) << 10) + (b1 >> 3);     // XCD swizzle over 8192
    const int lane = t & 63;
    const int gnode = __builtin_amdgcn_readfirstlane(bid * 16 + (t >> 6));
    const int b = gnode >> 10, d = gnode & 1023;

    const int p0 = __builtin_amdgcn_readfirstlane(ptrg[d]);
    const int p1 = __builtin_amdgcn_readfirstlane(ptrg[d + 1]);
    const int deg = p1 - p0;
    const char* gb = (const char*)(gsrc + (size_t)b * 65536);
    const unsigned lo = (unsigned)(lane << 1);
    const int2* pf = pkF + d * FSLOT;

    float acc0 = 0.f, acc1 = 0.f, acc2 = 0.f, acc3 = 0.f;

    {   // round 1: slots 0..15, all gathers independent
        int2 er[16];
#pragma unroll
        for (int i = 0; i < 16; ++i) er[i] = pf[i];
        float vv[16];
#pragma unroll
        for (int i = 0; i < 16; ++i)
            vv[i] = bf2f(*(const unsigned short*)(gb + (unsigned)er[i].y + lo));
#pragma unroll
        for (int i = 0; i < 16; i += 4) {
            acc0 += __int_as_float(er[i + 0].x) * vv[i + 0];
            acc1 += __int_as_float(er[i + 1].x) * vv[i + 1];
            acc2 += __int_as_float(er[i + 2].x) * vv[i + 2];
            acc3 += __int_as_float(er[i + 3].x) * vv[i + 3];
        }
    }
    if (deg > 16) {   // round 2: slots 16..31 (wave-uniform branch)
        int2 er[16];
#pragma unroll
        for (int i = 0; i < 16; ++i) er[i] = pf[16 + i];
        float vv[16];
#pragma unroll
        for (int i = 0; i < 16; ++i)
            vv[i] = bf2f(*(const unsigned short*)(gb + (unsigned)er[i].y + lo));
#pragma unroll
        for (int i = 0; i < 16; i += 4) {
            acc0 += __int_as_float(er[i + 0].x) * vv[i + 0];
            acc1 += __int_as_float(er[i + 1].x) * vv[i + 1];
            acc2 += __int_as_float(er[i + 2].x) * vv[i + 2];
            acc3 += __int_as_float(er[i + 3].x) * vv[i + 3];
        }
    }
    for (int p = p0 + FSLOT; p < p1; ++p) {   // rare tail (deg > 32)
        const int2 e = pk2[p];
        acc0 += __int_as_float(e.x) *
                bf2f(*(const unsigned short*)(gb + (unsigned)e.y + lo));
    }
    const float acc = (acc0 + acc1) + (acc2 + acc3);

    float xv;
    if (PASS == 1) xv = x[(size_t)gnode * 64 + lane];
    else           xv = bf2f(gsrc[(size_t)gnode * 64 + lane]);
    const float y = dgl[d] * xv - acc;
    tcat[(size_t)gnode * 192 + PASS * 64 + lane] = f2bf(y);
    if (PASS == 1) y1b[(size_t)gnode * 64 + lane] = f2bf(y);
}

// ---------------------------------------------------------------------------
// Weight conversion WITH lambda-scale folding (after lmax):
//   h = x(W0-W1+W2) + y1*s(W1-4W2) + y2*2s^2*W2,  s = 2/lmax.
// ---------------------------------------------------------------------------
__global__ __launch_bounds__(256) void k_cvtw(
    const float* __restrict__ chebW, const float* __restrict__ convW,
    const float* __restrict__ scal,
    unsigned short* __restrict__ wcatT, unsigned short* __restrict__ cvw)
{
    const int i = blockIdx.x * 256 + threadIdx.x;
    const float s = scal[1];
    if (i < 24576) {
        const int n = i / 192, kk = i % 192;
        const int k = kk & 63;
        const float w0 = chebW[k * 128 + n];
        const float w1 = chebW[8192 + k * 128 + n];
        const float w2 = chebW[16384 + k * 128 + n];
        float val;
        if (kk < 64)       val = w0 - w1 + w2;
        else if (kk < 128) val = s * (w1 - 4.f * w2);
        else               val = 2.f * s * s * w2;
        wcatT[i] = f2bf(val);
    }
    const int j = i - 24576;
    if (j >= 0 && j < 8192) cvw[j] = f2bf(convW[j]);
}

// ---------------------------------------------------------------------------
// bf16 MFMA fused cheb-GEMM + conv1d. Output bf16. (unchanged, proven)
// ---------------------------------------------------------------------------
__global__ __launch_bounds__(256) void k_cheb_mfma(
    const unsigned short* __restrict__ tcat,
    const unsigned short* __restrict__ wcatT,
    const unsigned short* __restrict__ cvw,
    const float* __restrict__ chebB, const float* __restrict__ convB,
    unsigned short* __restrict__ cout)
{
    __shared__ __align__(16) char smem[49152];
    __shared__ float cb_s[HID];
    __shared__ float cvb_s[C1];

    const int t    = threadIdx.x;
    const int lane = t & 63;
    const int wid  = t >> 6;
    const int l15  = lane & 15;
    const int l4   = lane >> 4;
    const int rbase = blockIdx.x * 128;
    const int bb = rbase >> 10;
    const int n0 = rbase & 1023;

    if (t < HID) cb_s[t] = chebB[t];
    if (t < C1)  cvb_s[t] = convB[t];

    for (int it = 0; it < 12; ++it) {
        const int gslot = it * 256 + t;
        const int n = gslot / 24, q = gslot % 24;
        const bf16x8 v = *(const bf16x8*)(wcatT + n * 192 + q * 8);
        *(bf16x8*)(smem + n * 384 + ((q ^ (n & 7)) << 4)) = v;
    }
    __syncthreads();

    const int rw = rbase + wid * 32;
    f32x4 acc[2][8];
#pragma unroll
    for (int m = 0; m < 2; ++m)
#pragma unroll
        for (int n = 0; n < 8; ++n) acc[m][n] = (f32x4)(0.f);

    const unsigned short* ta = tcat + (size_t)(rw + l15) * 192 + l4 * 8;
    bf16x8 a0 = *(const bf16x8*)(ta);
    bf16x8 a1 = *(const bf16x8*)(ta + 16 * 192);

#pragma unroll
    for (int ks = 0; ks < 6; ++ks) {
        bf16x8 na0, na1;
        if (ks < 5) {
            na0 = *(const bf16x8*)(ta + (ks + 1) * 32);
            na1 = *(const bf16x8*)(ta + 16 * 192 + (ks + 1) * 32);
        }
        const int kb = ks * 4 + l4;
#pragma unroll
        for (int nb = 0; nb < 8; ++nb) {
            const int n = nb * 16 + l15;
            const bf16x8 bv =
                *(const bf16x8*)(smem + n * 384 + ((kb ^ (n & 7)) << 4));
            acc[0][nb] = __builtin_amdgcn_mfma_f32_16x16x32_bf16(
                a0, bv, acc[0][nb], 0, 0, 0);
            acc[1][nb] = __builtin_amdgcn_mfma_f32_16x16x32_bf16(
                a1, bv, acc[1][nb], 0, 0, 0);
        }
        a0 = na0; a1 = na1;
    }
    __syncthreads();

#pragma unroll
    for (int mf = 0; mf < 2; ++mf)
#pragma unroll
        for (int nb = 0; nb < 8; ++nb) {
            const int c = nb * 16 + l15;
            const int slot = c >> 3;
            const float cb = cb_s[c];
#pragma unroll
            for (int reg = 0; reg < 4; ++reg) {
                const int node = wid * 32 + mf * 16 + l4 * 4 + reg;
                *(unsigned short*)(smem + node * 256 +
                                   ((slot ^ (node & 7)) << 4) + (c & 7) * 2) =
                    f2bf(acc[mf][nb][reg] + cb);
            }
        }
    for (int it = 0; it < 4; ++it) {
        const int gslot = it * 256 + t;
        const int c1i = gslot >> 4, q = gslot & 15;
        const bf16x8 v = *(const bf16x8*)(cvw + c1i * 128 + q * 8);
        *(bf16x8*)(smem + 32768 + c1i * 256 + ((q ^ (c1i & 7)) << 4)) = v;
    }
    __syncthreads();

    f32x4 acc2[8];
#pragma unroll
    for (int n = 0; n < 8; ++n) acc2[n] = (f32x4)(0.f);

#pragma unroll
    for (int ks = 0; ks < 4; ++ks) {
        const int kb = ks * 4 + l4;
        const int c1a = wid * 16 + l15;
        const bf16x8 av = *(const bf16x8*)(smem + 32768 + c1a * 256 +
                                           ((kb ^ (c1a & 7)) << 4));
#pragma unroll
        for (int nb = 0; nb < 8; ++nb) {
            const int node = nb * 16 + l15;
            const bf16x8 bv =
                *(const bf16x8*)(smem + node * 256 + ((kb ^ (node & 7)) << 4));
            acc2[nb] = __builtin_amdgcn_mfma_f32_16x16x32_bf16(
                av, bv, acc2[nb], 0, 0, 0);
        }
    }

#pragma unroll
    for (int nb = 0; nb < 8; ++nb) {
        const int ng = n0 + nb * 16 + l15;
#pragma unroll
        for (int reg = 0; reg < 4; ++reg) {
            const int c1i = wid * 16 + l4 * 4 + reg;
            cout[(size_t)bb * (C1 * NNODE) + (size_t)c1i * NNODE + ng] =
                f2bf(fmaxf(acc2[nb][reg] + cvb_s[c1i], 0.f));
        }
    }
}

// ---------------------------------------------------------------------------
// fc1 partials (K-split over 256-col chunks), bf16 input; reduce; head.
// ---------------------------------------------------------------------------
__global__ __launch_bounds__(256) void k_fc1(
    const unsigned short* __restrict__ cf, const float* __restrict__ W,
    float* __restrict__ part)
{
    __shared__ float Wt[256 * 33];
    const int t = threadIdx.x;
    const int g = blockIdx.x;
    const int k0 = g * 256;

    for (int i = t; i < 8192; i += 256) {
        const int j = i >> 8, k = i & 255;
        Wt[k * 33 + j] = W[(size_t)j * (C1 * NNODE) + k0 + k];
    }
    __syncthreads();

    const int j = t & 31, bg = t >> 5;
    float acc[16];
#pragma unroll
    for (int i = 0; i < 16; ++i) acc[i] = 0.f;

    const unsigned short* cb = cf + (size_t)(bg * 16) * (C1 * NNODE) + k0;
    for (int k4 = 0; k4 < 64; ++k4) {
        const int kb = k4 * 4;
        const float w0 = Wt[(kb + 0) * 33 + j];
        const float w1 = Wt[(kb + 1) * 33 + j];
        const float w2 = Wt[(kb + 2) * 33 + j];
        const float w3 = Wt[(kb + 3) * 33 + j];
#pragma unroll
        for (int i = 0; i < 16; ++i) {
            const u16x4 cv = *(const u16x4*)&cb[(size_t)i * (C1 * NNODE) + kb];
            acc[i] += bf2f(cv[0]) * w0 + bf2f(cv[1]) * w1 +
                      bf2f(cv[2]) * w2 + bf2f(cv[3]) * w3;
        }
    }
#pragma unroll
    for (int i = 0; i < 16; ++i)
        part[(size_t)g * 4096 + (size_t)(bg * 16 + i) * 32 + j] = acc[i];
}

__global__ __launch_bounds__(256) void k_red(
    const float* __restrict__ part, float* __restrict__ z)
{
    const int o = blockIdx.x * 256 + threadIdx.x;
    float s = 0.f;
    for (int g = 0; g < 256; ++g) s += part[(size_t)g * 4096 + o];
    z[o] = s;
}

__global__ __launch_bounds__(128) void k_head(
    const float* __restrict__ z, const float* __restrict__ b1,
    const float* __restrict__ W2, const float* __restrict__ b2,
    float* __restrict__ outp)
{
    const int b = threadIdx.x;
    float a[32];
#pragma unroll
    for (int j = 0; j < 32; ++j) a[j] = z[b * 32 + j] + b1[j];
    float l[4];
#pragma unroll
    for (int c = 0; c < 4; ++c) {
        float s = b2[c];
#pragma unroll
        for (int j = 0; j < 32; ++j) s += W2[c * 32 + j] * a[j];
        l[c] = s;
    }
    const float m = fmaxf(fmaxf(l[0], l[1]), fmaxf(l[2], l[3]));
    const float e0 = expf(l[0] - m), e1 = expf(l[1] - m);
    const float e2 = expf(l[2] - m), e3 = expf(l[3] - m);
    const float inv = 1.f / (e0 + e1 + e2 + e3);
    outp[b * 4 + 0] = e0 * inv;
    outp[b * 4 + 1] = e1 * inv;
    outp[b * 4 + 2] = e2 * inv;
    outp[b * 4 + 3] = e3 * inv;
}

// ---------------------------------------------------------------------------
extern "C" void kernel_launch(void* const* d_in, const int* in_sizes, int n_in,
                              void* d_out, int out_size, void* d_ws, size_t ws_size,
                              hipStream_t stream)
{
    const float* x     = (const float*)d_in[0];
    const int*   ei    = (const int*)d_in[1];
    const float* ew    = (const float*)d_in[2];
    const float* chebW = (const float*)d_in[3];
    const float* chebB = (const float*)d_in[4];
    const float* convW = (const float*)d_in[5];
    const float* convB = (const float*)d_in[6];
    const float* fc1W  = (const float*)d_in[7];
    const float* fc1B  = (const float*)d_in[8];
    const float* fc2W  = (const float*)d_in[9];
    const float* fc2B  = (const float*)d_in[10];
    float* out = (float*)d_out;

    char* ws = (char*)d_ws;
    float* scal   = (float*)(ws + 0);
    float* vstate = (float*)(ws + 4096);
    char*  partb  = ws + 8192;                      // 4MB multi-use region
    int*   cnt  = (int*)(partb + 4096);
    int*   pos  = (int*)(partb + 12288);
    int*   ptr  = (int*)(partb + 8192);             // overlaps neither cnt/pos
    float* dgr  = (float*)(partb + 16384);
    float* dgl  = (float*)(partb + 20480);
    int2*  pk   = (int2*)(partb + 24576);           // 128KB (raw w, src)
    unsigned short* wcatT = (unsigned short*)(partb + 262144);  // 48KB
    unsigned short* cvwB  = (unsigned short*)(partb + 327680);  // 16KB
    int2*  pk2  = (int2*)(partb + 458752);          // 128KB (relu w, src*128)
    int2*  pkF  = (int2*)(partb + 589824);          // 256KB fixed [1024][32]
    float* part = (float*)partb;                    // fc1 partials (after cheb)
    float* z    = (float*)(ws + 4202496);           // 64KB
    unsigned short* xb16 = (unsigned short*)(ws + 4268032);   // 16MB
    unsigned short* y1b  = (unsigned short*)(ws + 21045248);  // 16MB
    unsigned short* tcat = (unsigned short*)(ws + 37822464);  // 48MB
    unsigned short* cbuf = (unsigned short*)(ws + 88154112);  // 16MB

    // NOTE: ptr at partb+8192 (4KB+4B), cnt at +4096, pos at +12288: disjoint.
    k_zero <<<dim3(256), dim3(256), 0, stream>>>(cnt, dgr, dgl, pkF);
    k_count<<<dim3(64),  dim3(256), 0, stream>>>(ei, ew, cnt, dgr, dgl);
    k_scan <<<dim3(1),  dim3(1024), 0, stream>>>(cnt, ptr, pos);
    k_fill <<<dim3(64),  dim3(256), 0, stream>>>(ei, ew, ptr, pos, pk, pk2, pkF);

    k_xb <<<dim3(8192), dim3(256),  0, stream>>>(x, xb16, tcat);

    k_fused<1><<<dim3(8193), dim3(1024), 0, stream>>>(
        x, xb16, pk, pk2, pkF, ptr, dgr, dgl, vstate, scal, tcat, y1b);
    k_fused<2><<<dim3(8193), dim3(1024), 0, stream>>>(
        x, y1b, pk, pk2, pkF, ptr, dgr, dgl, vstate, scal, tcat, y1b);

    k_cvtw<<<dim3(128), dim3(256), 0, stream>>>(chebW, convW, scal, wcatT, cvwB);

    k_cheb_mfma<<<dim3(BN / 128), dim3(256), 0, stream>>>(
        tcat, wcatT, cvwB, chebB, convB, cbuf);

    k_fc1<<<dim3(256), dim3(256), 0, stream>>>(cbuf, fc1W, part);
    k_red<<<dim3(16), dim3(256), 0, stream>>>(part, z);
    k_head<<<dim3(1), dim3(128), 0, stream>>>(z, fc1B, fc2W, fc2B, out);
}